// Round 6
// baseline (1620.054 us; speedup 1.0000x reference)
//
#include <hip/hip_runtime.h>
#include <math.h>

namespace {
constexpr int B = 2;
constexpr int N = 2048;
constexpr int DIM = 512;
constexpr int H = 8;
constexpr int MEM = 16;
constexpr int J = MEM + N;       // 2064
constexpr int CHUNK = 256;
constexpr int CMAX = 9;          // ceil(2064/256)
constexpr float SCALE = 0.125f;
}

typedef __attribute__((ext_vector_type(8))) short short8;
typedef __attribute__((ext_vector_type(4))) float floatx4;
typedef __attribute__((ext_vector_type(8))) unsigned short ushortx8;

__device__ inline unsigned short f2bf(float f) {
    unsigned int u = __float_as_uint(f);
    u += 0x7fffu + ((u >> 16) & 1u);   // RNE
    return (unsigned short)(u >> 16);
}
__device__ inline unsigned int pk2bf(float a, float b) {
    return ((__float_as_uint(a) + 0x8000u) >> 16) |
           ((__float_as_uint(b) + 0x8000u) & 0xffff0000u);
}

// ---------------- P1: W [k][n] fp32 -> WT [n][k] bf16 (4 matrices) --------
__global__ __launch_bounds__(256)
void wt_conv(const float* __restrict__ Wq, const float* __restrict__ Wk,
             const float* __restrict__ Wv, const float* __restrict__ Wo,
             unsigned short* __restrict__ tq, unsigned short* __restrict__ tk,
             unsigned short* __restrict__ tv, unsigned short* __restrict__ to_)
{
    const int z = blockIdx.z;
    const float* __restrict__ W = (z == 0) ? Wq : (z == 1) ? Wk : (z == 2) ? Wv : Wo;
    unsigned short* __restrict__ WT = (z == 0) ? tq : (z == 1) ? tk : (z == 2) ? tv : to_;
    const int k0 = blockIdx.x * 64, n0 = blockIdx.y * 64;

    __shared__ __align__(16) unsigned short tile[64][72];
    const int t = threadIdx.x;
    const int rrow = t >> 4, rcol = (t & 15) * 4;
#pragma unroll
    for (int rr = 0; rr < 4; ++rr) {
        const int row = rrow + rr * 16;
        const float4 v = *(const float4*)(W + (size_t)(k0 + row) * DIM + n0 + rcol);
        tile[rcol + 0][row] = f2bf(v.x);
        tile[rcol + 1][row] = f2bf(v.y);
        tile[rcol + 2][row] = f2bf(v.z);
        tile[rcol + 3][row] = f2bf(v.w);
    }
    __syncthreads();
    const int orow = t >> 2, oseg = (t & 3) * 16;
    *(ushortx8*)(WT + (size_t)(n0 + orow) * DIM + k0 + oseg) =
        *(const ushortx8*)(&tile[orow][oseg]);
    *(ushortx8*)(WT + (size_t)(n0 + orow) * DIM + k0 + oseg + 8) =
        *(const ushortx8*)(&tile[orow][oseg + 8]);
}

// ---------------- K1: QKV projection GEMM (fp32 A inline-cvt, bf16 MFMA) --
__global__ __launch_bounds__(256)
void qkv_gemm(const float* __restrict__ x, const unsigned short* __restrict__ tq,
              const unsigned short* __restrict__ tk, const unsigned short* __restrict__ tv,
              unsigned short* __restrict__ q16, unsigned short* __restrict__ k16,
              unsigned short* __restrict__ vt16)
{
    const int which = blockIdx.z;
    const unsigned short* __restrict__ WT = (which == 0) ? tq : (which == 1) ? tk : tv;
    const int t = threadIdx.x;
    const int lane = t & 63, w = t >> 6;
    const int iL = lane & 15, quad = lane >> 4;
    const int mb = blockIdx.x * 64 + w * 16;
    const int n0 = blockIdx.y * 64;

    floatx4 acc[4];
#pragma unroll
    for (int ng = 0; ng < 4; ++ng) acc[ng] = (floatx4){0.f, 0.f, 0.f, 0.f};

    const float* arow = x + (size_t)(mb + iL) * DIM + quad * 8;
#pragma unroll 4
    for (int k0 = 0; k0 < DIM; k0 += 32) {
        const float4 a0 = *(const float4*)(arow + k0);
        const float4 a1 = *(const float4*)(arow + k0 + 4);
        const short8 af = { (short)f2bf(a0.x), (short)f2bf(a0.y), (short)f2bf(a0.z), (short)f2bf(a0.w),
                            (short)f2bf(a1.x), (short)f2bf(a1.y), (short)f2bf(a1.z), (short)f2bf(a1.w) };
#pragma unroll
        for (int ng = 0; ng < 4; ++ng) {
            const short8 bf = *(const short8*)(WT + (size_t)(n0 + ng * 16 + iL) * DIM + k0 + quad * 8);
            acc[ng] = __builtin_amdgcn_mfma_f32_16x16x32_bf16(af, bf, acc[ng], 0, 0, 0);
        }
    }

    const int h0 = n0 >> 6;
    if (which == 2) {
#pragma unroll
        for (int ng = 0; ng < 4; ++ng) {
            const int d = ng * 16 + iL;
#pragma unroll
            for (int r = 0; r < 4; ++r) {
                const int m = mb + quad * 4 + r;
                const int bb = m >> 11, ii = m & (N - 1);
                vt16[((size_t)(bb * H + h0) * 64 + d) * J + MEM + ii] = f2bf(acc[ng][r]);
            }
        }
    } else {
        unsigned short* dst = (which == 0) ? q16 : k16;
#pragma unroll
        for (int ng = 0; ng < 4; ++ng) {
            const int d = ng * 16 + iL;
#pragma unroll
            for (int r = 0; r < 4; ++r) {
                const int m = mb + quad * 4 + r;
                const int bb = m >> 11, ii = m & (N - 1);
                const size_t rowbase = (which == 0)
                    ? ((size_t)(bb * H + h0) * N + ii)
                    : ((size_t)(bb * H + h0) * J + MEM + ii);
                dst[rowbase * 64 + d] = f2bf(acc[ng][r]);
            }
        }
    }
}

// ---------------- K1b: mem_k/mem_v into k16 rows / vt16 cols 0..15 --------
__global__ void memkv_copy(const float* __restrict__ mem_k, const float* __restrict__ mem_v,
                           unsigned short* __restrict__ k16, unsigned short* __restrict__ vt16)
{
    const int idx = blockIdx.x * 256 + threadIdx.x;  // H*MEM*64 = 8192
    if (idx >= H * MEM * 64) return;
    const int h0 = idx >> 10;
    const int rd = idx & 1023;
    const int r = rd >> 6, d = rd & 63;
    const unsigned short kk = f2bf(mem_k[idx]);
    const unsigned short vv = f2bf(mem_v[idx]);
#pragma unroll
    for (int bb = 0; bb < B; ++bb) {
        k16[((size_t)(bb * H + h0) * J + r) * 64 + d] = kk;
        vt16[((size_t)(bb * H + h0) * 64 + d) * J + r] = vv;
    }
}

// ---------------- K2a: softmax denominators ------------------------------
__global__ __launch_bounds__(256, 4)
void attn_lsum(const unsigned short* __restrict__ qb, const unsigned short* __restrict__ kb,
               const float* __restrict__ prep, float* __restrict__ lbuf)
{
    const int c = blockIdx.x, tt = 127 - blockIdx.y, b = blockIdx.z;
    const int i0 = tt * 16;
    const int jlim = min(J, i0 + 32);
    const int jstart = c * CHUNK;
    if (jstart >= jlim) return;
    const int jend = min(jstart + CHUNK, jlim);

    __shared__ __align__(16) float pre_s[64];
    const int t = threadIdx.x;
    if (t < 64) pre_s[t] = prep[t];
    __syncthreads();

    const int lane = t & 63, w = t >> 6;
    const int iL = lane & 15, quad = lane >> 4;
    const int i = i0 + iL;

    short8 qf[H][2];
#pragma unroll
    for (int h = 0; h < H; ++h) {
        const unsigned short* qp = qb + ((size_t)(b * H + h) * N + i0 + iL) * 64 + quad * 8;
        qf[h][0] = *(const short8*)(qp);
        qf[h][1] = *(const short8*)(qp + 32);
    }

    float l_acc[H];
#pragma unroll
    for (int h1 = 0; h1 < H; ++h1) l_acc[h1] = 0.f;

    const int jw0 = jstart + w * 64;
    const int jw1 = min(jw0 + 64, jend);

    for (int j0 = jw0; j0 < jw1; j0 += 16) {
        floatx4 acc[H];
#pragma unroll
        for (int h = 0; h < H; ++h) {
            const unsigned short* kp = kb + ((size_t)(b * H + h) * J + j0 + iL) * 64 + quad * 8;
            floatx4 a = {0.f, 0.f, 0.f, 0.f};
            a = __builtin_amdgcn_mfma_f32_16x16x32_bf16(*(const short8*)kp, qf[h][0], a, 0, 0, 0);
            a = __builtin_amdgcn_mfma_f32_16x16x32_bf16(*(const short8*)(kp + 32), qf[h][1], a, 0, 0, 0);
            acc[h] = a;
        }
#pragma unroll
        for (int rp = 0; rp < 2; ++rp) {
            float dots[8][2];
#pragma unroll
            for (int h1 = 0; h1 < 8; ++h1) { dots[h1][0] = 0.f; dots[h1][1] = 0.f; }
#pragma unroll
            for (int h0 = 0; h0 < 8; ++h0) {
                const float4 pr0 = *(const float4*)(&pre_s[h0 * 8]);
                const float4 pr1 = *(const float4*)(&pre_s[h0 * 8 + 4]);
#pragma unroll
                for (int rr = 0; rr < 2; ++rr) {
                    const float a = acc[h0][rp * 2 + rr];
                    dots[0][rr] = fmaf(a, pr0.x, dots[0][rr]);
                    dots[1][rr] = fmaf(a, pr0.y, dots[1][rr]);
                    dots[2][rr] = fmaf(a, pr0.z, dots[2][rr]);
                    dots[3][rr] = fmaf(a, pr0.w, dots[3][rr]);
                    dots[4][rr] = fmaf(a, pr1.x, dots[4][rr]);
                    dots[5][rr] = fmaf(a, pr1.y, dots[5][rr]);
                    dots[6][rr] = fmaf(a, pr1.z, dots[6][rr]);
                    dots[7][rr] = fmaf(a, pr1.w, dots[7][rr]);
                }
            }
#pragma unroll
            for (int h1 = 0; h1 < 8; ++h1) {
                const float slope = exp2f(-(float)(h1 + 1));
#pragma unroll
                for (int rr = 0; rr < 2; ++rr) {
                    const int j = j0 + quad * 4 + rp * 2 + rr;
                    const bool vis = (j - MEM) <= i;
                    if (vis)
                        l_acc[h1] += __expf(fmaf(dots[h1][rr], SCALE, slope * (float)(j - i - MEM)));
                }
            }
        }
    }

#pragma unroll
    for (int h1 = 0; h1 < H; ++h1) {
        float v = l_acc[h1];
        v += __shfl_xor(v, 16);
        v += __shfl_xor(v, 32);
        if (quad == 0 && jw0 < jw1)
            atomicAdd(lbuf + ((size_t)(b * 128 + tt) * H + h1) * 16 + iL, v);
    }
}

// ---------------- K2b: PV with postmix (low-VGPR, hoisted mix rows) -------
__global__ __launch_bounds__(256, 4)
void attn_pv(const unsigned short* __restrict__ qb, const unsigned short* __restrict__ kb,
             const unsigned short* __restrict__ vt, const float* __restrict__ prep,
             const float* __restrict__ postp, const float* __restrict__ hsp,
             const float* __restrict__ lbuf, float* __restrict__ ao)
{
    const int c = blockIdx.x, tt = 127 - blockIdx.y, b = blockIdx.z;
    const int i0 = tt * 16;
    const int jlim = min(J, i0 + 32);
    const int jstart = c * CHUNK;
    if (jstart >= jlim) return;
    const int jend = min(jstart + CHUNK, jlim);

    __shared__ __align__(16) unsigned short p2s[H][16][136];
    __shared__ __align__(16) float pre_s[64];
    __shared__ __align__(16) float post_s[64];

    const int t = threadIdx.x;
    if (t < 64) { pre_s[t] = prep[t]; post_s[t] = postp[t] * hsp[t & 7]; }

    const int lane = t & 63, w = t >> 6;
    const int iL = lane & 15, quad = lane >> 4;
    const int i = i0 + iL;
    const int dW = w * 16 + iL;

    float linv[H];
#pragma unroll
    for (int h1 = 0; h1 < H; ++h1)
        linv[h1] = 1.0f / lbuf[((size_t)(b * 128 + tt) * H + h1) * 16 + iL];

    floatx4 y[H];
#pragma unroll
    for (int h2 = 0; h2 < H; ++h2) y[h2] = (floatx4){0.f, 0.f, 0.f, 0.f};
    __syncthreads();

    for (int jb0 = jstart; jb0 < jend; jb0 += 128) {
#pragma unroll
        for (int sub = 0; sub < 2; ++sub) {
            const int j0 = jb0 + w * 32 + sub * 16;
            const int colb = w * 32 + sub * 16 + quad * 4;
            if (j0 < jend) {
                floatx4 acc[H];
#pragma unroll
                for (int h = 0; h < H; ++h) {
                    const unsigned short* qp = qb + ((size_t)(b * H + h) * N + i0 + iL) * 64 + quad * 8;
                    const unsigned short* kp = kb + ((size_t)(b * H + h) * J + j0 + iL) * 64 + quad * 8;
                    floatx4 a = {0.f, 0.f, 0.f, 0.f};
                    a = __builtin_amdgcn_mfma_f32_16x16x32_bf16(*(const short8*)kp,
                                                                *(const short8*)qp, a, 0, 0, 0);
                    a = __builtin_amdgcn_mfma_f32_16x16x32_bf16(*(const short8*)(kp + 32),
                                                                *(const short8*)(qp + 32), a, 0, 0, 0);
                    acc[h] = a;
                }
#pragma unroll
                for (int rp = 0; rp < 2; ++rp) {
                    float dots[8][2];
#pragma unroll
                    for (int h1 = 0; h1 < 8; ++h1) { dots[h1][0] = 0.f; dots[h1][1] = 0.f; }
#pragma unroll
                    for (int h0 = 0; h0 < 8; ++h0) {
                        const float4 pr0 = *(const float4*)(&pre_s[h0 * 8]);
                        const float4 pr1 = *(const float4*)(&pre_s[h0 * 8 + 4]);
#pragma unroll
                        for (int rr = 0; rr < 2; ++rr) {
                            const float a = acc[h0][rp * 2 + rr];
                            dots[0][rr] = fmaf(a, pr0.x, dots[0][rr]);
                            dots[1][rr] = fmaf(a, pr0.y, dots[1][rr]);
                            dots[2][rr] = fmaf(a, pr0.z, dots[2][rr]);
                            dots[3][rr] = fmaf(a, pr0.w, dots[3][rr]);
                            dots[4][rr] = fmaf(a, pr1.x, dots[4][rr]);
                            dots[5][rr] = fmaf(a, pr1.y, dots[5][rr]);
                            dots[6][rr] = fmaf(a, pr1.z, dots[6][rr]);
                            dots[7][rr] = fmaf(a, pr1.w, dots[7][rr]);
                        }
                    }
                    float p2v[8][2];
#pragma unroll
                    for (int h2 = 0; h2 < 8; ++h2) { p2v[h2][0] = 0.f; p2v[h2][1] = 0.f; }
#pragma unroll
                    for (int h1 = 0; h1 < 8; ++h1) {
                        const float4 po0 = *(const float4*)(&post_s[h1 * 8]);
                        const float4 po1 = *(const float4*)(&post_s[h1 * 8 + 4]);
                        const float slope = exp2f(-(float)(h1 + 1));
#pragma unroll
                        for (int rr = 0; rr < 2; ++rr) {
                            const int j = j0 + quad * 4 + rp * 2 + rr;
                            const bool vis = (j - MEM) <= i;
                            const float e = vis
                                ? __expf(fmaf(dots[h1][rr], SCALE, slope * (float)(j - i - MEM))) * linv[h1]
                                : 0.f;
                            p2v[0][rr] = fmaf(e, po0.x, p2v[0][rr]);
                            p2v[1][rr] = fmaf(e, po0.y, p2v[1][rr]);
                            p2v[2][rr] = fmaf(e, po0.z, p2v[2][rr]);
                            p2v[3][rr] = fmaf(e, po0.w, p2v[3][rr]);
                            p2v[4][rr] = fmaf(e, po1.x, p2v[4][rr]);
                            p2v[5][rr] = fmaf(e, po1.y, p2v[5][rr]);
                            p2v[6][rr] = fmaf(e, po1.z, p2v[6][rr]);
                            p2v[7][rr] = fmaf(e, po1.w, p2v[7][rr]);
                        }
                    }
#pragma unroll
                    for (int h2 = 0; h2 < 8; ++h2)
                        *(unsigned int*)(&p2s[h2][iL][colb + rp * 2]) = pk2bf(p2v[h2][0], p2v[h2][1]);
                }
            } else {
#pragma unroll
                for (int h2 = 0; h2 < 8; ++h2) {
                    *(unsigned int*)(&p2s[h2][iL][colb]) = 0u;
                    *(unsigned int*)(&p2s[h2][iL][colb + 2]) = 0u;
                }
            }
        }
        __syncthreads();
        const int kcmax = (min(jend, jb0 + 128) - jb0 + 31) >> 5;
        for (int kc = 0; kc < kcmax; ++kc) {
            int jbv = jb0 + kc * 32 + quad * 8;
            if (jbv > J - 8) jbv = J - 8;   // masked region only; p2=0 there
#pragma unroll
            for (int h2 = 0; h2 < H; ++h2) {
                const short8 aF = *(const short8*)(&p2s[h2][iL][kc * 32 + quad * 8]);
                const short8 bF = *(const short8*)(vt + ((size_t)(b * H + h2) * 64 + dW) * J + jbv);
                y[h2] = __builtin_amdgcn_mfma_f32_16x16x32_bf16(aF, bF, y[h2], 0, 0, 0);
            }
        }
        __syncthreads();
    }

#pragma unroll
    for (int h2 = 0; h2 < H; ++h2) {
#pragma unroll
        for (int r = 0; r < 4; ++r) {
            const int ii = i0 + quad * 4 + r;
            atomicAdd(ao + ((size_t)b * N + ii) * DIM + h2 * 64 + dW, y[h2][r]);
        }
    }
}

// ---------------- K3: output projection GEMM + bias (fp32 A inline-cvt) ---
__global__ __launch_bounds__(256)
void out_gemm(const float* __restrict__ ain, const unsigned short* __restrict__ WT,
              const float* __restrict__ bo, float* __restrict__ out)
{
    const int t = threadIdx.x;
    const int lane = t & 63, w = t >> 6;
    const int iL = lane & 15, quad = lane >> 4;
    const int mb = blockIdx.x * 64 + w * 16;
    const int n0 = blockIdx.y * 64;

    floatx4 acc[4];
#pragma unroll
    for (int ng = 0; ng < 4; ++ng) acc[ng] = (floatx4){0.f, 0.f, 0.f, 0.f};

    const float* arow = ain + (size_t)(mb + iL) * DIM + quad * 8;
#pragma unroll 4
    for (int k0 = 0; k0 < DIM; k0 += 32) {
        const float4 a0 = *(const float4*)(arow + k0);
        const float4 a1 = *(const float4*)(arow + k0 + 4);
        const short8 af = { (short)f2bf(a0.x), (short)f2bf(a0.y), (short)f2bf(a0.z), (short)f2bf(a0.w),
                            (short)f2bf(a1.x), (short)f2bf(a1.y), (short)f2bf(a1.z), (short)f2bf(a1.w) };
#pragma unroll
        for (int ng = 0; ng < 4; ++ng) {
            const short8 bf = *(const short8*)(WT + (size_t)(n0 + ng * 16 + iL) * DIM + k0 + quad * 8);
            acc[ng] = __builtin_amdgcn_mfma_f32_16x16x32_bf16(af, bf, acc[ng], 0, 0, 0);
        }
    }

#pragma unroll
    for (int ng = 0; ng < 4; ++ng) {
        const int n = n0 + ng * 16 + iL;
        const float bias = bo[n];
#pragma unroll
        for (int r = 0; r < 4; ++r) {
            const int m = mb + quad * 4 + r;
            out[(size_t)m * DIM + n] = acc[ng][r] + bias;
        }
    }
}

extern "C" void kernel_launch(void* const* d_in, const int* in_sizes, int n_in,
                              void* d_out, int out_size, void* d_ws, size_t ws_size,
                              hipStream_t stream)
{
    (void)in_sizes; (void)n_in; (void)out_size; (void)ws_size;
    const float* x      = (const float*)d_in[0];
    const float* Wq     = (const float*)d_in[1];
    const float* Wk     = (const float*)d_in[2];
    const float* Wv     = (const float*)d_in[3];
    const float* mem_k  = (const float*)d_in[4];
    const float* mem_v  = (const float*)d_in[5];
    const float* pre_p  = (const float*)d_in[6];
    const float* post_p = (const float*)d_in[7];
    const float* hs     = (const float*)d_in[8];
    const float* Wo     = (const float*)d_in[9];
    const float* bo     = (const float*)d_in[10];
    float* out = (float*)d_out;

    constexpr size_t NAO  = (size_t)B * N * DIM;        // 2,097,152
    constexpr size_t NLB  = (size_t)B * 128 * H * 16;   //    32,768
    constexpr size_t NW   = (size_t)DIM * DIM;          //   262,144
    constexpr size_t NQ   = (size_t)B * H * N * 64;     // 2,097,152
    constexpr size_t NK   = (size_t)B * H * J * 64;     // 2,113,536

    float* ws = (float*)d_ws;
    float* ao   = ws;
    float* lbuf = ao + NAO;
    unsigned short* wtq  = (unsigned short*)(lbuf + NLB);
    unsigned short* wtk  = wtq + NW;
    unsigned short* wtv  = wtk + NW;
    unsigned short* wto  = wtv + NW;
    unsigned short* q16  = wto + NW;
    unsigned short* k16  = q16 + NQ;
    unsigned short* v16  = k16 + NK;

    wt_conv<<<dim3(8, 8, 4), 256, 0, stream>>>(Wq, Wk, Wv, Wo, wtq, wtk, wtv, wto);
    qkv_gemm<<<dim3(64, 8, 3), 256, 0, stream>>>(x, wtq, wtk, wtv, q16, k16, v16);
    memkv_copy<<<dim3(32), 256, 0, stream>>>(mem_k, mem_v, k16, v16);
    hipMemsetAsync(ao, 0, (NAO + NLB) * sizeof(float), stream);
    attn_lsum<<<dim3(CMAX, 128, B), 256, 0, stream>>>(q16, k16, pre_p, lbuf);
    attn_pv<<<dim3(CMAX, 128, B), 256, 0, stream>>>(q16, k16, v16, pre_p, post_p, hs, lbuf, ao);
    out_gemm<<<dim3(64, 8), 256, 0, stream>>>(ao, wto, bo, out);
}

// Round 7
// 429.568 us; speedup vs baseline: 3.7714x; 3.7714x over previous
//
#include <hip/hip_runtime.h>
#include <math.h>

namespace {
constexpr int B = 2;
constexpr int N = 2048;
constexpr int DIM = 512;
constexpr int H = 8;
constexpr int MEM = 16;
constexpr int J = MEM + N;       // 2064
constexpr int CHUNK = 256;
constexpr int CMAX = 9;          // ceil(2064/256)
constexpr float S2 = 0.125f * 1.4426950408889634f;  // SCALE * log2(e)
}

typedef __attribute__((ext_vector_type(8))) short short8;
typedef __attribute__((ext_vector_type(4))) float floatx4;
typedef __attribute__((ext_vector_type(8))) unsigned short ushortx8;

__device__ inline unsigned short f2bf(float f) {
    unsigned int u = __float_as_uint(f);
    u += 0x7fffu + ((u >> 16) & 1u);   // RNE
    return (unsigned short)(u >> 16);
}
__device__ inline unsigned int pk2bf(float a, float b) {
    return ((__float_as_uint(a) + 0x8000u) >> 16) |
           ((__float_as_uint(b) + 0x8000u) & 0xffff0000u);
}

// ---------------- P1: W [k][n] fp32 -> WT [n][k] bf16 (4 matrices) --------
__global__ __launch_bounds__(256)
void wt_conv(const float* __restrict__ Wq, const float* __restrict__ Wk,
             const float* __restrict__ Wv, const float* __restrict__ Wo,
             unsigned short* __restrict__ tq, unsigned short* __restrict__ tk,
             unsigned short* __restrict__ tv, unsigned short* __restrict__ to_)
{
    const int z = blockIdx.z;
    const float* __restrict__ W = (z == 0) ? Wq : (z == 1) ? Wk : (z == 2) ? Wv : Wo;
    unsigned short* __restrict__ WT = (z == 0) ? tq : (z == 1) ? tk : (z == 2) ? tv : to_;
    const int k0 = blockIdx.x * 64, n0 = blockIdx.y * 64;

    __shared__ __align__(16) unsigned short tile[64][72];
    const int t = threadIdx.x;
    const int rrow = t >> 4, rcol = (t & 15) * 4;
#pragma unroll
    for (int rr = 0; rr < 4; ++rr) {
        const int row = rrow + rr * 16;
        const float4 v = *(const float4*)(W + (size_t)(k0 + row) * DIM + n0 + rcol);
        tile[rcol + 0][row] = f2bf(v.x);
        tile[rcol + 1][row] = f2bf(v.y);
        tile[rcol + 2][row] = f2bf(v.z);
        tile[rcol + 3][row] = f2bf(v.w);
    }
    __syncthreads();
    const int orow = t >> 2, oseg = (t & 3) * 16;
    *(ushortx8*)(WT + (size_t)(n0 + orow) * DIM + k0 + oseg) =
        *(const ushortx8*)(&tile[orow][oseg]);
    *(ushortx8*)(WT + (size_t)(n0 + orow) * DIM + k0 + oseg + 8) =
        *(const ushortx8*)(&tile[orow][oseg + 8]);
}

// ---------------- K1: QKV projection GEMM (fp32 A inline-cvt, bf16 MFMA) --
__global__ __launch_bounds__(256)
void qkv_gemm(const float* __restrict__ x, const unsigned short* __restrict__ tq,
              const unsigned short* __restrict__ tk, const unsigned short* __restrict__ tv,
              unsigned short* __restrict__ q16, unsigned short* __restrict__ k16,
              unsigned short* __restrict__ vt16)
{
    const int which = blockIdx.z;
    const unsigned short* __restrict__ WT = (which == 0) ? tq : (which == 1) ? tk : tv;
    const int t = threadIdx.x;
    const int lane = t & 63, w = t >> 6;
    const int iL = lane & 15, quad = lane >> 4;
    const int mb = blockIdx.x * 64 + w * 16;
    const int n0 = blockIdx.y * 64;

    floatx4 acc[4];
#pragma unroll
    for (int ng = 0; ng < 4; ++ng) acc[ng] = (floatx4){0.f, 0.f, 0.f, 0.f};

    const float* arow = x + (size_t)(mb + iL) * DIM + quad * 8;
#pragma unroll 4
    for (int k0 = 0; k0 < DIM; k0 += 32) {
        const float4 a0 = *(const float4*)(arow + k0);
        const float4 a1 = *(const float4*)(arow + k0 + 4);
        const short8 af = { (short)f2bf(a0.x), (short)f2bf(a0.y), (short)f2bf(a0.z), (short)f2bf(a0.w),
                            (short)f2bf(a1.x), (short)f2bf(a1.y), (short)f2bf(a1.z), (short)f2bf(a1.w) };
#pragma unroll
        for (int ng = 0; ng < 4; ++ng) {
            const short8 bf = *(const short8*)(WT + (size_t)(n0 + ng * 16 + iL) * DIM + k0 + quad * 8);
            acc[ng] = __builtin_amdgcn_mfma_f32_16x16x32_bf16(af, bf, acc[ng], 0, 0, 0);
        }
    }

    const int h0 = n0 >> 6;
    if (which == 2) {
#pragma unroll
        for (int ng = 0; ng < 4; ++ng) {
            const int d = ng * 16 + iL;
#pragma unroll
            for (int r = 0; r < 4; ++r) {
                const int m = mb + quad * 4 + r;
                const int bb = m >> 11, ii = m & (N - 1);
                vt16[((size_t)(bb * H + h0) * 64 + d) * J + MEM + ii] = f2bf(acc[ng][r]);
            }
        }
    } else {
        unsigned short* dst = (which == 0) ? q16 : k16;
#pragma unroll
        for (int ng = 0; ng < 4; ++ng) {
            const int d = ng * 16 + iL;
#pragma unroll
            for (int r = 0; r < 4; ++r) {
                const int m = mb + quad * 4 + r;
                const int bb = m >> 11, ii = m & (N - 1);
                const size_t rowbase = (which == 0)
                    ? ((size_t)(bb * H + h0) * N + ii)
                    : ((size_t)(bb * H + h0) * J + MEM + ii);
                dst[rowbase * 64 + d] = f2bf(acc[ng][r]);
            }
        }
    }
}

// ---------------- K1b: mem_k/mem_v into k16 rows / vt16 cols 0..15 --------
__global__ void memkv_copy(const float* __restrict__ mem_k, const float* __restrict__ mem_v,
                           unsigned short* __restrict__ k16, unsigned short* __restrict__ vt16)
{
    const int idx = blockIdx.x * 256 + threadIdx.x;  // H*MEM*64 = 8192
    if (idx >= H * MEM * 64) return;
    const int h0 = idx >> 10;
    const int rd = idx & 1023;
    const int r = rd >> 6, d = rd & 63;
    const unsigned short kk = f2bf(mem_k[idx]);
    const unsigned short vv = f2bf(mem_v[idx]);
#pragma unroll
    for (int bb = 0; bb < B; ++bb) {
        k16[((size_t)(bb * H + h0) * J + r) * 64 + d] = kk;
        vt16[((size_t)(bb * H + h0) * 64 + d) * J + r] = vv;
    }
}

// ---------------- K2a: softmax denominators (streaming premix) ------------
__global__ __launch_bounds__(256)
void attn_lsum(const unsigned short* __restrict__ qb, const unsigned short* __restrict__ kb,
               const float* __restrict__ prep, float* __restrict__ lbuf)
{
    const int c = blockIdx.x, tt = 127 - blockIdx.y, b = blockIdx.z;
    const int i0 = tt * 16;
    const int jlim = min(J, i0 + 32);
    const int jstart = c * CHUNK;
    if (jstart >= jlim) return;
    const int jend = min(jstart + CHUNK, jlim);

    __shared__ __align__(16) float pre_s[64];
    const int t = threadIdx.x;
    if (t < 64) pre_s[t] = prep[t];
    __syncthreads();

    const int lane = t & 63, w = t >> 6;
    const int iL = lane & 15, quad = lane >> 4;
    const int i = i0 + iL;

    float l_acc[H];
#pragma unroll
    for (int h1 = 0; h1 < H; ++h1) l_acc[h1] = 0.f;

    int joff = 0;
    bool any = false;
    // interleaved 16-col strips: wave w takes j0 = jstart + (4*step+w)*16
    for (int j0 = jstart + w * 16; j0 < jend; j0 += 64) {
        any = true;
        asm volatile("" : "+v"(joff));   // stop q/k load hoisting across iters
        float dots[8][4];
#pragma unroll
        for (int h1 = 0; h1 < 8; ++h1)
#pragma unroll
            for (int r = 0; r < 4; ++r) dots[h1][r] = 0.f;
#pragma unroll
        for (int h0 = 0; h0 < 8; ++h0) {
            const unsigned short* qp = qb + ((size_t)(b * H + h0) * N + i0 + iL) * 64 + quad * 8 + joff;
            const unsigned short* kp = kb + ((size_t)(b * H + h0) * J + j0 + iL) * 64 + quad * 8 + joff;
            floatx4 a = {0.f, 0.f, 0.f, 0.f};
            a = __builtin_amdgcn_mfma_f32_16x16x32_bf16(*(const short8*)kp,
                                                        *(const short8*)qp, a, 0, 0, 0);
            a = __builtin_amdgcn_mfma_f32_16x16x32_bf16(*(const short8*)(kp + 32),
                                                        *(const short8*)(qp + 32), a, 0, 0, 0);
            const float4 pr0 = *(const float4*)(&pre_s[h0 * 8]);
            const float4 pr1 = *(const float4*)(&pre_s[h0 * 8 + 4]);
#pragma unroll
            for (int r = 0; r < 4; ++r) {
                const float av = a[r];
                dots[0][r] = fmaf(av, pr0.x, dots[0][r]);
                dots[1][r] = fmaf(av, pr0.y, dots[1][r]);
                dots[2][r] = fmaf(av, pr0.z, dots[2][r]);
                dots[3][r] = fmaf(av, pr0.w, dots[3][r]);
                dots[4][r] = fmaf(av, pr1.x, dots[4][r]);
                dots[5][r] = fmaf(av, pr1.y, dots[5][r]);
                dots[6][r] = fmaf(av, pr1.z, dots[6][r]);
                dots[7][r] = fmaf(av, pr1.w, dots[7][r]);
            }
        }
#pragma unroll
        for (int h1 = 0; h1 < 8; ++h1) {
            const float slopeE = 1.4426950408889634f / (float)(2 << h1);
#pragma unroll
            for (int r = 0; r < 4; ++r) {
                const int j = j0 + quad * 4 + r;
                if ((j - MEM) <= i)
                    l_acc[h1] += exp2f(fmaf(dots[h1][r], S2, slopeE * (float)(j - i - MEM)));
            }
        }
    }

#pragma unroll
    for (int h1 = 0; h1 < H; ++h1) {
        float v = l_acc[h1];
        v += __shfl_xor(v, 16);
        v += __shfl_xor(v, 32);
        if (quad == 0 && any)
            atomicAdd(lbuf + ((size_t)(b * 128 + tt) * H + h1) * 16 + iL, v);
    }
}

// ---------------- K2b: PV with postmix (streaming premix, window=64) ------
__global__ __launch_bounds__(256)
void attn_pv(const unsigned short* __restrict__ qb, const unsigned short* __restrict__ kb,
             const unsigned short* __restrict__ vt, const float* __restrict__ prep,
             const float* __restrict__ postp, const float* __restrict__ hsp,
             const float* __restrict__ lbuf, float* __restrict__ ao)
{
    const int c = blockIdx.x, tt = 127 - blockIdx.y, b = blockIdx.z;
    const int i0 = tt * 16;
    const int jlim = min(J, i0 + 32);
    const int jstart = c * CHUNK;
    if (jstart >= jlim) return;
    const int jend = min(jstart + CHUNK, jlim);

    __shared__ __align__(16) unsigned short p2s[H][16][72];  // window=64 (+8 pad)
    __shared__ __align__(16) float pre_s[64];
    __shared__ __align__(16) float post_s[64];

    const int t = threadIdx.x;
    if (t < 64) { pre_s[t] = prep[t]; post_s[t] = postp[t] * hsp[t & 7]; }

    const int lane = t & 63, w = t >> 6;
    const int iL = lane & 15, quad = lane >> 4;
    const int i = i0 + iL;
    const int dW = w * 16 + iL;   // this wave's d for PV

    float linv[H];
#pragma unroll
    for (int h1 = 0; h1 < H; ++h1)
        linv[h1] = 1.0f / lbuf[((size_t)(b * 128 + tt) * H + h1) * 16 + iL];

    floatx4 y[H];
#pragma unroll
    for (int h2 = 0; h2 < H; ++h2) y[h2] = (floatx4){0.f, 0.f, 0.f, 0.f};
    __syncthreads();

    int joff = 0;
    for (int jb0 = jstart; jb0 < jend; jb0 += 64) {
        asm volatile("" : "+v"(joff));   // stop q/k load hoisting across windows
        const int j0 = jb0 + w * 16;     // this wave's 16-col slice of the window
        const int colb = w * 16 + quad * 4;
        if (j0 < jend) {
            float dots[8][4];
#pragma unroll
            for (int h1 = 0; h1 < 8; ++h1)
#pragma unroll
                for (int r = 0; r < 4; ++r) dots[h1][r] = 0.f;
#pragma unroll
            for (int h0 = 0; h0 < 8; ++h0) {
                const unsigned short* qp = qb + ((size_t)(b * H + h0) * N + i0 + iL) * 64 + quad * 8 + joff;
                const unsigned short* kp = kb + ((size_t)(b * H + h0) * J + j0 + iL) * 64 + quad * 8 + joff;
                floatx4 a = {0.f, 0.f, 0.f, 0.f};
                a = __builtin_amdgcn_mfma_f32_16x16x32_bf16(*(const short8*)kp,
                                                            *(const short8*)qp, a, 0, 0, 0);
                a = __builtin_amdgcn_mfma_f32_16x16x32_bf16(*(const short8*)(kp + 32),
                                                            *(const short8*)(qp + 32), a, 0, 0, 0);
                const float4 pr0 = *(const float4*)(&pre_s[h0 * 8]);
                const float4 pr1 = *(const float4*)(&pre_s[h0 * 8 + 4]);
#pragma unroll
                for (int r = 0; r < 4; ++r) {
                    const float av = a[r];
                    dots[0][r] = fmaf(av, pr0.x, dots[0][r]);
                    dots[1][r] = fmaf(av, pr0.y, dots[1][r]);
                    dots[2][r] = fmaf(av, pr0.z, dots[2][r]);
                    dots[3][r] = fmaf(av, pr0.w, dots[3][r]);
                    dots[4][r] = fmaf(av, pr1.x, dots[4][r]);
                    dots[5][r] = fmaf(av, pr1.y, dots[5][r]);
                    dots[6][r] = fmaf(av, pr1.z, dots[6][r]);
                    dots[7][r] = fmaf(av, pr1.w, dots[7][r]);
                }
            }
            float p2v[8][4];
#pragma unroll
            for (int h2 = 0; h2 < 8; ++h2)
#pragma unroll
                for (int r = 0; r < 4; ++r) p2v[h2][r] = 0.f;
#pragma unroll
            for (int h1 = 0; h1 < 8; ++h1) {
                const float slopeE = 1.4426950408889634f / (float)(2 << h1);
                const float4 po0 = *(const float4*)(&post_s[h1 * 8]);
                const float4 po1 = *(const float4*)(&post_s[h1 * 8 + 4]);
#pragma unroll
                for (int r = 0; r < 4; ++r) {
                    const int j = j0 + quad * 4 + r;
                    const bool vis = (j - MEM) <= i;
                    const float e = vis
                        ? exp2f(fmaf(dots[h1][r], S2, slopeE * (float)(j - i - MEM))) * linv[h1]
                        : 0.f;
                    p2v[0][r] = fmaf(e, po0.x, p2v[0][r]);
                    p2v[1][r] = fmaf(e, po0.y, p2v[1][r]);
                    p2v[2][r] = fmaf(e, po0.z, p2v[2][r]);
                    p2v[3][r] = fmaf(e, po0.w, p2v[3][r]);
                    p2v[4][r] = fmaf(e, po1.x, p2v[4][r]);
                    p2v[5][r] = fmaf(e, po1.y, p2v[5][r]);
                    p2v[6][r] = fmaf(e, po1.z, p2v[6][r]);
                    p2v[7][r] = fmaf(e, po1.w, p2v[7][r]);
                }
            }
#pragma unroll
            for (int h2 = 0; h2 < 8; ++h2) {
                *(unsigned int*)(&p2s[h2][iL][colb]) = pk2bf(p2v[h2][0], p2v[h2][1]);
                *(unsigned int*)(&p2s[h2][iL][colb + 2]) = pk2bf(p2v[h2][2], p2v[h2][3]);
            }
        } else {
#pragma unroll
            for (int h2 = 0; h2 < 8; ++h2) {
                *(unsigned int*)(&p2s[h2][iL][colb]) = 0u;
                *(unsigned int*)(&p2s[h2][iL][colb + 2]) = 0u;
            }
        }
        __syncthreads();
        // ---- PV phase: wave w owns d-strip [w*16, w*16+16) over the window ----
#pragma unroll
        for (int kc = 0; kc < 2; ++kc) {
            int jbv = jb0 + kc * 32 + quad * 8;
            if (jbv > J - 8) jbv = J - 8;   // masked region only; p2=0 there
#pragma unroll
            for (int h2 = 0; h2 < H; ++h2) {
                const short8 aF = *(const short8*)(&p2s[h2][iL][kc * 32 + quad * 8]);
                const short8 bF = *(const short8*)(vt + ((size_t)(b * H + h2) * 64 + dW) * J + jbv);
                y[h2] = __builtin_amdgcn_mfma_f32_16x16x32_bf16(aF, bF, y[h2], 0, 0, 0);
            }
        }
        __syncthreads();
    }

#pragma unroll
    for (int h2 = 0; h2 < H; ++h2) {
#pragma unroll
        for (int r = 0; r < 4; ++r) {
            const int ii = i0 + quad * 4 + r;
            atomicAdd(ao + ((size_t)b * N + ii) * DIM + h2 * 64 + dW, y[h2][r]);
        }
    }
}

// ---------------- K3: output projection GEMM + bias (fp32 A inline-cvt) ---
__global__ __launch_bounds__(256)
void out_gemm(const float* __restrict__ ain, const unsigned short* __restrict__ WT,
              const float* __restrict__ bo, float* __restrict__ out)
{
    const int t = threadIdx.x;
    const int lane = t & 63, w = t >> 6;
    const int iL = lane & 15, quad = lane >> 4;
    const int mb = blockIdx.x * 64 + w * 16;
    const int n0 = blockIdx.y * 64;

    floatx4 acc[4];
#pragma unroll
    for (int ng = 0; ng < 4; ++ng) acc[ng] = (floatx4){0.f, 0.f, 0.f, 0.f};

    const float* arow = ain + (size_t)(mb + iL) * DIM + quad * 8;
#pragma unroll 4
    for (int k0 = 0; k0 < DIM; k0 += 32) {
        const float4 a0 = *(const float4*)(arow + k0);
        const float4 a1 = *(const float4*)(arow + k0 + 4);
        const short8 af = { (short)f2bf(a0.x), (short)f2bf(a0.y), (short)f2bf(a0.z), (short)f2bf(a0.w),
                            (short)f2bf(a1.x), (short)f2bf(a1.y), (short)f2bf(a1.z), (short)f2bf(a1.w) };
#pragma unroll
        for (int ng = 0; ng < 4; ++ng) {
            const short8 bf = *(const short8*)(WT + (size_t)(n0 + ng * 16 + iL) * DIM + k0 + quad * 8);
            acc[ng] = __builtin_amdgcn_mfma_f32_16x16x32_bf16(af, bf, acc[ng], 0, 0, 0);
        }
    }

#pragma unroll
    for (int ng = 0; ng < 4; ++ng) {
        const int n = n0 + ng * 16 + iL;
        const float bias = bo[n];
#pragma unroll
        for (int r = 0; r < 4; ++r) {
            const int m = mb + quad * 4 + r;
            out[(size_t)m * DIM + n] = acc[ng][r] + bias;
        }
    }
}

extern "C" void kernel_launch(void* const* d_in, const int* in_sizes, int n_in,
                              void* d_out, int out_size, void* d_ws, size_t ws_size,
                              hipStream_t stream)
{
    (void)in_sizes; (void)n_in; (void)out_size; (void)ws_size;
    const float* x      = (const float*)d_in[0];
    const float* Wq     = (const float*)d_in[1];
    const float* Wk     = (const float*)d_in[2];
    const float* Wv     = (const float*)d_in[3];
    const float* mem_k  = (const float*)d_in[4];
    const float* mem_v  = (const float*)d_in[5];
    const float* pre_p  = (const float*)d_in[6];
    const float* post_p = (const float*)d_in[7];
    const float* hs     = (const float*)d_in[8];
    const float* Wo     = (const float*)d_in[9];
    const float* bo     = (const float*)d_in[10];
    float* out = (float*)d_out;

    constexpr size_t NAO  = (size_t)B * N * DIM;        // 2,097,152
    constexpr size_t NLB  = (size_t)B * 128 * H * 16;   //    32,768
    constexpr size_t NW   = (size_t)DIM * DIM;          //   262,144
    constexpr size_t NQ   = (size_t)B * H * N * 64;     // 2,097,152
    constexpr size_t NK   = (size_t)B * H * J * 64;     // 2,113,536

    float* ws = (float*)d_ws;
    float* ao   = ws;
    float* lbuf = ao + NAO;
    unsigned short* wtq  = (unsigned short*)(lbuf + NLB);
    unsigned short* wtk  = wtq + NW;
    unsigned short* wtv  = wtk + NW;
    unsigned short* wto  = wtv + NW;
    unsigned short* q16  = wto + NW;
    unsigned short* k16  = q16 + NQ;
    unsigned short* v16  = k16 + NK;

    wt_conv<<<dim3(8, 8, 4), 256, 0, stream>>>(Wq, Wk, Wv, Wo, wtq, wtk, wtv, wto);
    qkv_gemm<<<dim3(64, 8, 3), 256, 0, stream>>>(x, wtq, wtk, wtv, q16, k16, v16);
    memkv_copy<<<dim3(32), 256, 0, stream>>>(mem_k, mem_v, k16, v16);
    hipMemsetAsync(ao, 0, (NAO + NLB) * sizeof(float), stream);
    attn_lsum<<<dim3(CMAX, 128, B), 256, 0, stream>>>(q16, k16, pre_p, lbuf);
    attn_pv<<<dim3(CMAX, 128, B), 256, 0, stream>>>(q16, k16, v16, pre_p, post_p, hs, lbuf, ao);
    out_gemm<<<dim3(64, 8), 256, 0, stream>>>(ao, wto, bo, out);
}

// Round 8
// 314.452 us; speedup vs baseline: 5.1520x; 1.3661x over previous
//
#include <hip/hip_runtime.h>
#include <math.h>

namespace {
constexpr int B = 2;
constexpr int N = 2048;
constexpr int DIM = 512;
constexpr int H = 8;
constexpr int MEM = 16;
constexpr int J = MEM + N;       // 2064
constexpr int CHUNK = 256;
constexpr int CMAX = 9;          // ceil(2064/256)
constexpr float S2 = 0.125f * 1.4426950408889634f;  // SCALE * log2(e)
// e-buffer: per b, sum_t (16t+32) j-rows * 16 i * 8 h1 bf16 elems
constexpr size_t EPB = 17170432;        // 134144 * 128
constexpr size_t NE  = 2 * EPB;         // 34,340,864 u16 = 68.7 MB
}

typedef __attribute__((ext_vector_type(8))) short short8;
typedef __attribute__((ext_vector_type(4))) float floatx4;
typedef __attribute__((ext_vector_type(8))) unsigned short ushortx8;

__device__ inline unsigned short f2bf(float f) {
    unsigned int u = __float_as_uint(f);
    u += 0x7fffu + ((u >> 16) & 1u);   // RNE
    return (unsigned short)(u >> 16);
}
__device__ inline unsigned int pk2bf(float a, float b) {
    return ((__float_as_uint(a) + 0x8000u) >> 16) |
           ((__float_as_uint(b) + 0x8000u) & 0xffff0000u);
}

// ---------------- P1: W [k][n] fp32 -> WT [n][k] bf16 (4 matrices) --------
__global__ __launch_bounds__(256)
void wt_conv(const float* __restrict__ Wq, const float* __restrict__ Wk,
             const float* __restrict__ Wv, const float* __restrict__ Wo,
             unsigned short* __restrict__ tq, unsigned short* __restrict__ tk,
             unsigned short* __restrict__ tv, unsigned short* __restrict__ to_)
{
    const int z = blockIdx.z;
    const float* __restrict__ W = (z == 0) ? Wq : (z == 1) ? Wk : (z == 2) ? Wv : Wo;
    unsigned short* __restrict__ WT = (z == 0) ? tq : (z == 1) ? tk : (z == 2) ? tv : to_;
    const int k0 = blockIdx.x * 64, n0 = blockIdx.y * 64;

    __shared__ __align__(16) unsigned short tile[64][72];
    const int t = threadIdx.x;
    const int rrow = t >> 4, rcol = (t & 15) * 4;
#pragma unroll
    for (int rr = 0; rr < 4; ++rr) {
        const int row = rrow + rr * 16;
        const float4 v = *(const float4*)(W + (size_t)(k0 + row) * DIM + n0 + rcol);
        tile[rcol + 0][row] = f2bf(v.x);
        tile[rcol + 1][row] = f2bf(v.y);
        tile[rcol + 2][row] = f2bf(v.z);
        tile[rcol + 3][row] = f2bf(v.w);
    }
    __syncthreads();
    const int orow = t >> 2, oseg = (t & 3) * 16;
    *(ushortx8*)(WT + (size_t)(n0 + orow) * DIM + k0 + oseg) =
        *(const ushortx8*)(&tile[orow][oseg]);
    *(ushortx8*)(WT + (size_t)(n0 + orow) * DIM + k0 + oseg + 8) =
        *(const ushortx8*)(&tile[orow][oseg + 8]);
}

// ---------------- K1: QKV projection GEMM (fp32 A inline-cvt, bf16 MFMA) --
__global__ __launch_bounds__(256)
void qkv_gemm(const float* __restrict__ x, const unsigned short* __restrict__ tq,
              const unsigned short* __restrict__ tk, const unsigned short* __restrict__ tv,
              unsigned short* __restrict__ q16, unsigned short* __restrict__ k16,
              unsigned short* __restrict__ vt16)
{
    const int which = blockIdx.z;
    const unsigned short* __restrict__ WT = (which == 0) ? tq : (which == 1) ? tk : tv;
    const int t = threadIdx.x;
    const int lane = t & 63, w = t >> 6;
    const int iL = lane & 15, quad = lane >> 4;
    const int mb = blockIdx.x * 64 + w * 16;
    const int n0 = blockIdx.y * 64;

    floatx4 acc[4];
#pragma unroll
    for (int ng = 0; ng < 4; ++ng) acc[ng] = (floatx4){0.f, 0.f, 0.f, 0.f};

    const float* arow = x + (size_t)(mb + iL) * DIM + quad * 8;
#pragma unroll 4
    for (int k0 = 0; k0 < DIM; k0 += 32) {
        const float4 a0 = *(const float4*)(arow + k0);
        const float4 a1 = *(const float4*)(arow + k0 + 4);
        const short8 af = { (short)f2bf(a0.x), (short)f2bf(a0.y), (short)f2bf(a0.z), (short)f2bf(a0.w),
                            (short)f2bf(a1.x), (short)f2bf(a1.y), (short)f2bf(a1.z), (short)f2bf(a1.w) };
#pragma unroll
        for (int ng = 0; ng < 4; ++ng) {
            const short8 bf = *(const short8*)(WT + (size_t)(n0 + ng * 16 + iL) * DIM + k0 + quad * 8);
            acc[ng] = __builtin_amdgcn_mfma_f32_16x16x32_bf16(af, bf, acc[ng], 0, 0, 0);
        }
    }

    const int h0 = n0 >> 6;
    if (which == 2) {
#pragma unroll
        for (int ng = 0; ng < 4; ++ng) {
            const int d = ng * 16 + iL;
#pragma unroll
            for (int r = 0; r < 4; ++r) {
                const int m = mb + quad * 4 + r;
                const int bb = m >> 11, ii = m & (N - 1);
                vt16[((size_t)(bb * H + h0) * 64 + d) * J + MEM + ii] = f2bf(acc[ng][r]);
            }
        }
    } else {
        unsigned short* dst = (which == 0) ? q16 : k16;
#pragma unroll
        for (int ng = 0; ng < 4; ++ng) {
            const int d = ng * 16 + iL;
#pragma unroll
            for (int r = 0; r < 4; ++r) {
                const int m = mb + quad * 4 + r;
                const int bb = m >> 11, ii = m & (N - 1);
                const size_t rowbase = (which == 0)
                    ? ((size_t)(bb * H + h0) * N + ii)
                    : ((size_t)(bb * H + h0) * J + MEM + ii);
                dst[rowbase * 64 + d] = f2bf(acc[ng][r]);
            }
        }
    }
}

// ---------------- K1b: mem_k/mem_v into k16 rows / vt16 cols 0..15 --------
__global__ void memkv_copy(const float* __restrict__ mem_k, const float* __restrict__ mem_v,
                           unsigned short* __restrict__ k16, unsigned short* __restrict__ vt16)
{
    const int idx = blockIdx.x * 256 + threadIdx.x;  // H*MEM*64 = 8192
    if (idx >= H * MEM * 64) return;
    const int h0 = idx >> 10;
    const int rd = idx & 1023;
    const int r = rd >> 6, d = rd & 63;
    const unsigned short kk = f2bf(mem_k[idx]);
    const unsigned short vv = f2bf(mem_v[idx]);
#pragma unroll
    for (int bb = 0; bb < B; ++bb) {
        k16[((size_t)(bb * H + h0) * J + r) * 64 + d] = kk;
        vt16[((size_t)(bb * H + h0) * 64 + d) * J + r] = vv;
    }
}

// ---------------- K2a: scores pass — QK + premix + exp; store e; sum l ----
// e layout: ebase(b,tt) + (j*16 + i)*8 + h1   (bf16, 16B per (i,j) pair)
__global__ __launch_bounds__(256)
void attn_scores(const unsigned short* __restrict__ qb, const unsigned short* __restrict__ kb,
                 const float* __restrict__ prep, float* __restrict__ lbuf,
                 unsigned short* __restrict__ e16)
{
    const int c = blockIdx.x, tt = 127 - blockIdx.y, b = blockIdx.z;
    const int i0 = tt * 16;
    const int jlim = i0 + 32;            // == min(J, i0+32) for all tt
    const int jstart = c * CHUNK;
    if (jstart >= jlim) return;
    const int jend = min(jstart + CHUNK, jlim);

    __shared__ __align__(16) float pre_s[64];
    const int t = threadIdx.x;
    if (t < 64) pre_s[t] = prep[t];
    __syncthreads();

    const int lane = t & 63, w = t >> 6;
    const int iL = lane & 15, quad = lane >> 4;
    const int i = i0 + iL;
    const size_t ebase = (size_t)b * EPB + (size_t)(8 * tt * tt + 24 * tt) * 128;

    float l_acc[8];
#pragma unroll
    for (int h1 = 0; h1 < 8; ++h1) l_acc[h1] = 0.f;

    bool any = false;
    for (int j0 = jstart + w * 16; j0 < jend; j0 += 64) {
        any = true;
        float dots[8][4];
#pragma unroll
        for (int h1 = 0; h1 < 8; ++h1)
#pragma unroll
            for (int r = 0; r < 4; ++r) dots[h1][r] = 0.f;
#pragma unroll
        for (int h0 = 0; h0 < 8; ++h0) {
            const unsigned short* qp = qb + ((size_t)(b * H + h0) * N + i0 + iL) * 64 + quad * 8;
            const unsigned short* kp = kb + ((size_t)(b * H + h0) * J + j0 + iL) * 64 + quad * 8;
            floatx4 a = {0.f, 0.f, 0.f, 0.f};
            a = __builtin_amdgcn_mfma_f32_16x16x32_bf16(*(const short8*)kp,
                                                        *(const short8*)qp, a, 0, 0, 0);
            a = __builtin_amdgcn_mfma_f32_16x16x32_bf16(*(const short8*)(kp + 32),
                                                        *(const short8*)(qp + 32), a, 0, 0, 0);
            const float4 pr0 = *(const float4*)(&pre_s[h0 * 8]);
            const float4 pr1 = *(const float4*)(&pre_s[h0 * 8 + 4]);
#pragma unroll
            for (int r = 0; r < 4; ++r) {
                const float av = a[r];
                dots[0][r] = fmaf(av, pr0.x, dots[0][r]);
                dots[1][r] = fmaf(av, pr0.y, dots[1][r]);
                dots[2][r] = fmaf(av, pr0.z, dots[2][r]);
                dots[3][r] = fmaf(av, pr0.w, dots[3][r]);
                dots[4][r] = fmaf(av, pr1.x, dots[4][r]);
                dots[5][r] = fmaf(av, pr1.y, dots[5][r]);
                dots[6][r] = fmaf(av, pr1.z, dots[6][r]);
                dots[7][r] = fmaf(av, pr1.w, dots[7][r]);
            }
        }
        unsigned int epk[4][4];
        float etmp[4];
#pragma unroll
        for (int h1 = 0; h1 < 8; ++h1) {
            const float slopeE = 1.4426950408889634f / (float)(2 << h1);
#pragma unroll
            for (int r = 0; r < 4; ++r) {
                const int j = j0 + quad * 4 + r;
                const bool vis = (j - MEM) <= i;
                const float e = vis ? exp2f(fmaf(dots[h1][r], S2, slopeE * (float)(j - i - MEM)))
                                    : 0.f;
                l_acc[h1] += e;
                if (h1 & 1) epk[r][h1 >> 1] = pk2bf(etmp[r], e);
                else        etmp[r] = e;
            }
        }
#pragma unroll
        for (int r = 0; r < 4; ++r) {
            uint4 o = make_uint4(epk[r][0], epk[r][1], epk[r][2], epk[r][3]);
            *(uint4*)(e16 + ebase + (size_t)((j0 + quad * 4 + r) * 16 + iL) * 8) = o;
        }
    }

#pragma unroll
    for (int h1 = 0; h1 < 8; ++h1) {
        float v = l_acc[h1];
        v += __shfl_xor(v, 16);
        v += __shfl_xor(v, 32);
        if (quad == 0 && any)
            atomicAdd(lbuf + ((size_t)(b * 128 + tt) * 8 + h1) * 16 + iL, v);
    }
}

// ---------------- K2b: pv pass — load e, normalize, postmix, PV-MFMA ------
__global__ __launch_bounds__(256)
void attn_pv2(const unsigned short* __restrict__ e16, const unsigned short* __restrict__ vt,
              const float* __restrict__ postp, const float* __restrict__ hsp,
              const float* __restrict__ lbuf, float* __restrict__ ao)
{
    const int c = blockIdx.x, tt = 127 - blockIdx.y, b = blockIdx.z;
    const int i0 = tt * 16;
    const int jlim = i0 + 32;
    const int jstart = c * CHUNK;
    if (jstart >= jlim) return;
    const int jend = min(jstart + CHUNK, jlim);

    __shared__ __align__(16) unsigned short p2s[8][16][40];  // 32-j window (+8 pad)
    __shared__ __align__(16) float post_s[64];

    const int t = threadIdx.x;
    if (t < 64) post_s[t] = postp[t] * hsp[t & 7];

    const int lane = t & 63, w = t >> 6;
    const int iL = lane & 15, quad = lane >> 4;
    const int dW = w * 16 + iL;          // consumer d
    const int i_p = t & 15;              // producer i
    const int jj = t >> 4;               // producer j-group (0..15)
    const size_t ebase = (size_t)b * EPB + (size_t)(8 * tt * tt + 24 * tt) * 128;

    float linv[8];
#pragma unroll
    for (int h1 = 0; h1 < 8; ++h1)
        linv[h1] = 1.0f / lbuf[((size_t)(b * 128 + tt) * 8 + h1) * 16 + i_p];

    floatx4 y[8];
#pragma unroll
    for (int h2 = 0; h2 < 8; ++h2) y[h2] = (floatx4){0.f, 0.f, 0.f, 0.f};
    __syncthreads();

    for (int jw0 = jstart; jw0 < jend; jw0 += 32) {
        float p2[2][8];
#pragma unroll
        for (int s = 0; s < 2; ++s) {
#pragma unroll
            for (int h2 = 0; h2 < 8; ++h2) p2[s][h2] = 0.f;
            const int j = jw0 + jj * 2 + s;
            if (j < jend) {
                const ushortx8 ev = *(const ushortx8*)(e16 + ebase + (size_t)(j * 16 + i_p) * 8);
#pragma unroll
                for (int h1 = 0; h1 < 8; ++h1) {
                    const float e = __uint_as_float((unsigned int)ev[h1] << 16) * linv[h1];
                    const float4 po0 = *(const float4*)(&post_s[h1 * 8]);
                    const float4 po1 = *(const float4*)(&post_s[h1 * 8 + 4]);
                    p2[s][0] = fmaf(e, po0.x, p2[s][0]);
                    p2[s][1] = fmaf(e, po0.y, p2[s][1]);
                    p2[s][2] = fmaf(e, po0.z, p2[s][2]);
                    p2[s][3] = fmaf(e, po0.w, p2[s][3]);
                    p2[s][4] = fmaf(e, po1.x, p2[s][4]);
                    p2[s][5] = fmaf(e, po1.y, p2[s][5]);
                    p2[s][6] = fmaf(e, po1.z, p2[s][6]);
                    p2[s][7] = fmaf(e, po1.w, p2[s][7]);
                }
            }
        }
#pragma unroll
        for (int h2 = 0; h2 < 8; ++h2)
            *(unsigned int*)(&p2s[h2][i_p][jj * 2]) = pk2bf(p2[0][h2], p2[1][h2]);
        __syncthreads();

        int jbv = jw0 + quad * 8;
        if (jbv > J - 8) jbv = J - 8;    // only masked cols land here; p2s=0 for them
#pragma unroll
        for (int h2 = 0; h2 < 8; ++h2) {
            const short8 aF = *(const short8*)(&p2s[h2][iL][quad * 8]);
            const short8 bF = *(const short8*)(vt + ((size_t)(b * H + h2) * 64 + dW) * J + jbv);
            y[h2] = __builtin_amdgcn_mfma_f32_16x16x32_bf16(aF, bF, y[h2], 0, 0, 0);
        }
        __syncthreads();
    }

#pragma unroll
    for (int h2 = 0; h2 < 8; ++h2) {
#pragma unroll
        for (int r = 0; r < 4; ++r) {
            const int ii = i0 + quad * 4 + r;
            atomicAdd(ao + ((size_t)b * N + ii) * DIM + h2 * 64 + dW, y[h2][r]);
        }
    }
}

// ---------------- K3: output projection GEMM + bias (fp32 A inline-cvt) ---
__global__ __launch_bounds__(256)
void out_gemm(const float* __restrict__ ain, const unsigned short* __restrict__ WT,
              const float* __restrict__ bo, float* __restrict__ out)
{
    const int t = threadIdx.x;
    const int lane = t & 63, w = t >> 6;
    const int iL = lane & 15, quad = lane >> 4;
    const int mb = blockIdx.x * 64 + w * 16;
    const int n0 = blockIdx.y * 64;

    floatx4 acc[4];
#pragma unroll
    for (int ng = 0; ng < 4; ++ng) acc[ng] = (floatx4){0.f, 0.f, 0.f, 0.f};

    const float* arow = ain + (size_t)(mb + iL) * DIM + quad * 8;
#pragma unroll 4
    for (int k0 = 0; k0 < DIM; k0 += 32) {
        const float4 a0 = *(const float4*)(arow + k0);
        const float4 a1 = *(const float4*)(arow + k0 + 4);
        const short8 af = { (short)f2bf(a0.x), (short)f2bf(a0.y), (short)f2bf(a0.z), (short)f2bf(a0.w),
                            (short)f2bf(a1.x), (short)f2bf(a1.y), (short)f2bf(a1.z), (short)f2bf(a1.w) };
#pragma unroll
        for (int ng = 0; ng < 4; ++ng) {
            const short8 bf = *(const short8*)(WT + (size_t)(n0 + ng * 16 + iL) * DIM + k0 + quad * 8);
            acc[ng] = __builtin_amdgcn_mfma_f32_16x16x32_bf16(af, bf, acc[ng], 0, 0, 0);
        }
    }

#pragma unroll
    for (int ng = 0; ng < 4; ++ng) {
        const int n = n0 + ng * 16 + iL;
        const float bias = bo[n];
#pragma unroll
        for (int r = 0; r < 4; ++r) {
            const int m = mb + quad * 4 + r;
            out[(size_t)m * DIM + n] = acc[ng][r] + bias;
        }
    }
}

extern "C" void kernel_launch(void* const* d_in, const int* in_sizes, int n_in,
                              void* d_out, int out_size, void* d_ws, size_t ws_size,
                              hipStream_t stream)
{
    (void)in_sizes; (void)n_in; (void)out_size; (void)ws_size;
    const float* x      = (const float*)d_in[0];
    const float* Wq     = (const float*)d_in[1];
    const float* Wk     = (const float*)d_in[2];
    const float* Wv     = (const float*)d_in[3];
    const float* mem_k  = (const float*)d_in[4];
    const float* mem_v  = (const float*)d_in[5];
    const float* pre_p  = (const float*)d_in[6];
    const float* post_p = (const float*)d_in[7];
    const float* hs     = (const float*)d_in[8];
    const float* Wo     = (const float*)d_in[9];
    const float* bo     = (const float*)d_in[10];
    float* out = (float*)d_out;

    constexpr size_t NAO  = (size_t)B * N * DIM;        // 2,097,152 f32
    constexpr size_t NLB  = (size_t)B * 128 * H * 16;   //    32,768 f32
    constexpr size_t NW   = (size_t)DIM * DIM;          //   262,144 u16 each
    constexpr size_t NQ   = (size_t)B * H * N * 64;     // 2,097,152 u16
    constexpr size_t NK   = (size_t)B * H * J * 64;     // 2,113,536 u16
    // total ws usage ~= 92 MB (e-buffer 68.7 MB)

    float* ws = (float*)d_ws;
    float* ao   = ws;
    float* lbuf = ao + NAO;
    unsigned short* wtq  = (unsigned short*)(lbuf + NLB);
    unsigned short* wtk  = wtq + NW;
    unsigned short* wtv  = wtk + NW;
    unsigned short* wto  = wtv + NW;
    unsigned short* q16  = wto + NW;
    unsigned short* k16  = q16 + NQ;
    unsigned short* v16  = k16 + NK;
    unsigned short* e16  = v16 + NK;

    wt_conv<<<dim3(8, 8, 4), 256, 0, stream>>>(Wq, Wk, Wv, Wo, wtq, wtk, wtv, wto);
    qkv_gemm<<<dim3(64, 8, 3), 256, 0, stream>>>(x, wtq, wtk, wtv, q16, k16, v16);
    memkv_copy<<<dim3(32), 256, 0, stream>>>(mem_k, mem_v, k16, v16);
    hipMemsetAsync(ao, 0, (NAO + NLB) * sizeof(float), stream);
    attn_scores<<<dim3(CMAX, 128, B), 256, 0, stream>>>(q16, k16, pre_p, lbuf, e16);
    attn_pv2<<<dim3(CMAX, 128, B), 256, 0, stream>>>(e16, v16, post_p, hs, lbuf, ao);
    out_gemm<<<dim3(64, 8), 256, 0, stream>>>(ao, wto, bo, out);
}

// Round 9
// 301.411 us; speedup vs baseline: 5.3749x; 1.0433x over previous
//
#include <hip/hip_runtime.h>
#include <math.h>

namespace {
constexpr int B = 2;
constexpr int N = 2048;
constexpr int DIM = 512;
constexpr int H = 8;
constexpr int MEM = 16;
constexpr int J = MEM + N;       // 2064
constexpr int CHUNK = 256;
constexpr int CMAX = 9;          // ceil(2064/256)
constexpr float S2 = 0.125f * 1.4426950408889634f;  // SCALE * log2(e)
// e-buffer: per b, sum_t (16t+32) j-rows * 16 i * 8 h1 bf16 elems
constexpr size_t EPB = 17170432;        // 134144 * 128
}

typedef __attribute__((ext_vector_type(8))) short short8;
typedef __attribute__((ext_vector_type(4))) float floatx4;
typedef __attribute__((ext_vector_type(8))) unsigned short ushortx8;

__device__ inline unsigned short f2bf(float f) {
    unsigned int u = __float_as_uint(f);
    u += 0x7fffu + ((u >> 16) & 1u);   // RNE
    return (unsigned short)(u >> 16);
}
__device__ inline unsigned int pk2bf(float a, float b) {
    return ((__float_as_uint(a) + 0x8000u) >> 16) |
           ((__float_as_uint(b) + 0x8000u) & 0xffff0000u);
}

// ---------------- P1: W [k][n] fp32 -> WT [n][k] bf16 (4 matrices) --------
__global__ __launch_bounds__(256)
void wt_conv(const float* __restrict__ Wq, const float* __restrict__ Wk,
             const float* __restrict__ Wv, const float* __restrict__ Wo,
             unsigned short* __restrict__ tq, unsigned short* __restrict__ tk,
             unsigned short* __restrict__ tv, unsigned short* __restrict__ to_)
{
    const int z = blockIdx.z;
    const float* __restrict__ W = (z == 0) ? Wq : (z == 1) ? Wk : (z == 2) ? Wv : Wo;
    unsigned short* __restrict__ WT = (z == 0) ? tq : (z == 1) ? tk : (z == 2) ? tv : to_;
    const int k0 = blockIdx.x * 64, n0 = blockIdx.y * 64;

    __shared__ __align__(16) unsigned short tile[64][72];
    const int t = threadIdx.x;
    const int rrow = t >> 4, rcol = (t & 15) * 4;
#pragma unroll
    for (int rr = 0; rr < 4; ++rr) {
        const int row = rrow + rr * 16;
        const float4 v = *(const float4*)(W + (size_t)(k0 + row) * DIM + n0 + rcol);
        tile[rcol + 0][row] = f2bf(v.x);
        tile[rcol + 1][row] = f2bf(v.y);
        tile[rcol + 2][row] = f2bf(v.z);
        tile[rcol + 3][row] = f2bf(v.w);
    }
    __syncthreads();
    const int orow = t >> 2, oseg = (t & 3) * 16;
    *(ushortx8*)(WT + (size_t)(n0 + orow) * DIM + k0 + oseg) =
        *(const ushortx8*)(&tile[orow][oseg]);
    *(ushortx8*)(WT + (size_t)(n0 + orow) * DIM + k0 + oseg + 8) =
        *(const ushortx8*)(&tile[orow][oseg + 8]);
}

// ---------------- K1: QKV projection GEMM (fp32 A inline-cvt, bf16 MFMA) --
__global__ __launch_bounds__(256)
void qkv_gemm(const float* __restrict__ x, const unsigned short* __restrict__ tq,
              const unsigned short* __restrict__ tk, const unsigned short* __restrict__ tv,
              unsigned short* __restrict__ q16, unsigned short* __restrict__ k16,
              unsigned short* __restrict__ vt16)
{
    const int which = blockIdx.z;
    const unsigned short* __restrict__ WT = (which == 0) ? tq : (which == 1) ? tk : tv;
    const int t = threadIdx.x;
    const int lane = t & 63, w = t >> 6;
    const int iL = lane & 15, quad = lane >> 4;
    const int mb = blockIdx.x * 64 + w * 16;
    const int n0 = blockIdx.y * 64;

    floatx4 acc[4];
#pragma unroll
    for (int ng = 0; ng < 4; ++ng) acc[ng] = (floatx4){0.f, 0.f, 0.f, 0.f};

    const float* arow = x + (size_t)(mb + iL) * DIM + quad * 8;
#pragma unroll 4
    for (int k0 = 0; k0 < DIM; k0 += 32) {
        const float4 a0 = *(const float4*)(arow + k0);
        const float4 a1 = *(const float4*)(arow + k0 + 4);
        const short8 af = { (short)f2bf(a0.x), (short)f2bf(a0.y), (short)f2bf(a0.z), (short)f2bf(a0.w),
                            (short)f2bf(a1.x), (short)f2bf(a1.y), (short)f2bf(a1.z), (short)f2bf(a1.w) };
#pragma unroll
        for (int ng = 0; ng < 4; ++ng) {
            const short8 bf = *(const short8*)(WT + (size_t)(n0 + ng * 16 + iL) * DIM + k0 + quad * 8);
            acc[ng] = __builtin_amdgcn_mfma_f32_16x16x32_bf16(af, bf, acc[ng], 0, 0, 0);
        }
    }

    const int h0 = n0 >> 6;
    if (which == 2) {
#pragma unroll
        for (int ng = 0; ng < 4; ++ng) {
            const int d = ng * 16 + iL;
#pragma unroll
            for (int r = 0; r < 4; ++r) {
                const int m = mb + quad * 4 + r;
                const int bb = m >> 11, ii = m & (N - 1);
                vt16[((size_t)(bb * H + h0) * 64 + d) * J + MEM + ii] = f2bf(acc[ng][r]);
            }
        }
    } else {
        unsigned short* dst = (which == 0) ? q16 : k16;
#pragma unroll
        for (int ng = 0; ng < 4; ++ng) {
            const int d = ng * 16 + iL;
#pragma unroll
            for (int r = 0; r < 4; ++r) {
                const int m = mb + quad * 4 + r;
                const int bb = m >> 11, ii = m & (N - 1);
                const size_t rowbase = (which == 0)
                    ? ((size_t)(bb * H + h0) * N + ii)
                    : ((size_t)(bb * H + h0) * J + MEM + ii);
                dst[rowbase * 64 + d] = f2bf(acc[ng][r]);
            }
        }
    }
}

// ---------------- K1b: mem_k/mem_v into k16 rows / vt16 cols 0..15 --------
__global__ void memkv_copy(const float* __restrict__ mem_k, const float* __restrict__ mem_v,
                           unsigned short* __restrict__ k16, unsigned short* __restrict__ vt16)
{
    const int idx = blockIdx.x * 256 + threadIdx.x;  // H*MEM*64 = 8192
    if (idx >= H * MEM * 64) return;
    const int h0 = idx >> 10;
    const int rd = idx & 1023;
    const int r = rd >> 6, d = rd & 63;
    const unsigned short kk = f2bf(mem_k[idx]);
    const unsigned short vv = f2bf(mem_v[idx]);
#pragma unroll
    for (int bb = 0; bb < B; ++bb) {
        k16[((size_t)(bb * H + h0) * J + r) * 64 + d] = kk;
        vt16[((size_t)(bb * H + h0) * 64 + d) * J + r] = vv;
    }
}

// ---------------- K2a: scores pass — QK + premix + exp; store e; sum l ----
// q-tile staged in LDS; k fragments prefetched one h0 ahead.
__global__ __launch_bounds__(256)
void attn_scores(const unsigned short* __restrict__ qb, const unsigned short* __restrict__ kb,
                 const float* __restrict__ prep, float* __restrict__ lbuf,
                 unsigned short* __restrict__ e16)
{
    const int c = blockIdx.x, tt = 127 - blockIdx.y, b = blockIdx.z;
    const int i0 = tt * 16;
    const int jlim = i0 + 32;            // == min(J, i0+32) for all tt
    const int jstart = c * CHUNK;
    if (jstart >= jlim) return;
    const int jend = min(jstart + CHUNK, jlim);

    __shared__ __align__(16) unsigned short q_s[8][16][64];  // 16 KB
    __shared__ __align__(16) float pre_s[64];
    const int t = threadIdx.x;
    if (t < 64) pre_s[t] = prep[t];
    // cooperative q-tile load: 8192 u16, 8 per thread per iter
#pragma unroll
    for (int u4 = 0; u4 < 4; ++u4) {
        const int u = t + u4 * 256;          // over 1024 groups of 8
        const int h = u >> 7, rem = u & 127, i = rem >> 3, seg = (rem & 7) * 8;
        *(ushortx8*)(&q_s[h][i][seg]) =
            *(const ushortx8*)(qb + ((size_t)(b * H + h) * N + i0 + i) * 64 + seg);
    }
    __syncthreads();

    const int lane = t & 63, w = t >> 6;
    const int iL = lane & 15, quad = lane >> 4;
    const int i = i0 + iL;
    const size_t ebase = (size_t)b * EPB + (size_t)(8 * tt * tt + 24 * tt) * 128;

    float l_acc[8];
#pragma unroll
    for (int h1 = 0; h1 < 8; ++h1) l_acc[h1] = 0.f;

    bool any = false;
    for (int j0 = jstart + w * 16; j0 < jend; j0 += 64) {
        any = true;
        float dots[8][4];
#pragma unroll
        for (int h1 = 0; h1 < 8; ++h1)
#pragma unroll
            for (int r = 0; r < 4; ++r) dots[h1][r] = 0.f;

        // k prefetch chain over h0
        const unsigned short* kp0 = kb + ((size_t)(b * H) * J + j0 + iL) * 64 + quad * 8;
        short8 kc0 = *(const short8*)kp0;
        short8 kc1 = *(const short8*)(kp0 + 32);
#pragma unroll
        for (int h0 = 0; h0 < 8; ++h0) {
            short8 kn0, kn1;
            if (h0 < 7) {
                const unsigned short* kpn =
                    kb + ((size_t)(b * H + h0 + 1) * J + j0 + iL) * 64 + quad * 8;
                kn0 = *(const short8*)kpn;
                kn1 = *(const short8*)(kpn + 32);
            }
            const short8 qf0 = *(const short8*)(&q_s[h0][iL][quad * 8]);
            const short8 qf1 = *(const short8*)(&q_s[h0][iL][quad * 8 + 32]);
            floatx4 a = {0.f, 0.f, 0.f, 0.f};
            a = __builtin_amdgcn_mfma_f32_16x16x32_bf16(kc0, qf0, a, 0, 0, 0);
            a = __builtin_amdgcn_mfma_f32_16x16x32_bf16(kc1, qf1, a, 0, 0, 0);
            const float4 pr0 = *(const float4*)(&pre_s[h0 * 8]);
            const float4 pr1 = *(const float4*)(&pre_s[h0 * 8 + 4]);
#pragma unroll
            for (int r = 0; r < 4; ++r) {
                const float av = a[r];
                dots[0][r] = fmaf(av, pr0.x, dots[0][r]);
                dots[1][r] = fmaf(av, pr0.y, dots[1][r]);
                dots[2][r] = fmaf(av, pr0.z, dots[2][r]);
                dots[3][r] = fmaf(av, pr0.w, dots[3][r]);
                dots[4][r] = fmaf(av, pr1.x, dots[4][r]);
                dots[5][r] = fmaf(av, pr1.y, dots[5][r]);
                dots[6][r] = fmaf(av, pr1.z, dots[6][r]);
                dots[7][r] = fmaf(av, pr1.w, dots[7][r]);
            }
            kc0 = kn0; kc1 = kn1;
        }

        unsigned int epk[4][4];
        float etmp[4];
#pragma unroll
        for (int h1 = 0; h1 < 8; ++h1) {
            const float slopeE = 1.4426950408889634f / (float)(2 << h1);
#pragma unroll
            for (int r = 0; r < 4; ++r) {
                const int j = j0 + quad * 4 + r;
                const bool vis = (j - MEM) <= i;
                const float e = vis ? exp2f(fmaf(dots[h1][r], S2, slopeE * (float)(j - i - MEM)))
                                    : 0.f;
                l_acc[h1] += e;
                if (h1 & 1) epk[r][h1 >> 1] = pk2bf(etmp[r], e);
                else        etmp[r] = e;
            }
        }
#pragma unroll
        for (int r = 0; r < 4; ++r) {
            uint4 o = make_uint4(epk[r][0], epk[r][1], epk[r][2], epk[r][3]);
            *(uint4*)(e16 + ebase + (size_t)((j0 + quad * 4 + r) * 16 + iL) * 8) = o;
        }
    }

#pragma unroll
    for (int h1 = 0; h1 < 8; ++h1) {
        float v = l_acc[h1];
        v += __shfl_xor(v, 16);
        v += __shfl_xor(v, 32);
        if (quad == 0 && any)
            atomicAdd(lbuf + ((size_t)(b * 128 + tt) * 8 + h1) * 16 + iL, v);
    }
}

// ---------------- K2b: pv pass — pipelined e-load, dbuf LDS, PV-MFMA ------
__global__ __launch_bounds__(256)
void attn_pv2(const unsigned short* __restrict__ e16, const unsigned short* __restrict__ vt,
              const float* __restrict__ postp, const float* __restrict__ hsp,
              const float* __restrict__ lbuf, float* __restrict__ ao)
{
    const int c = blockIdx.x, tt = 127 - blockIdx.y, b = blockIdx.z;
    const int i0 = tt * 16;
    const int jlim = i0 + 32;
    const int jstart = c * CHUNK;
    if (jstart >= jlim) return;
    const int jend = min(jstart + CHUNK, jlim);
    const int nw = (jend - jstart + 31) >> 5;   // 32-j windows (<=8)

    __shared__ __align__(16) unsigned short p2s[2][8][16][40];  // double buffer
    __shared__ __align__(16) float post_s[64];

    const int t = threadIdx.x;
    if (t < 64) post_s[t] = postp[t] * hsp[t & 7];

    const int lane = t & 63, w = t >> 6;
    const int iL = lane & 15, quad = lane >> 4;
    const int dW = w * 16 + iL;          // consumer d
    const int i_p = t & 15;              // producer i
    const int jj = t >> 4;               // producer j-group (0..15)
    const size_t ebase = (size_t)b * EPB + (size_t)(8 * tt * tt + 24 * tt) * 128;

    float linv[8];
#pragma unroll
    for (int h1 = 0; h1 < 8; ++h1)
        linv[h1] = 1.0f / lbuf[((size_t)(b * 128 + tt) * 8 + h1) * 16 + i_p];

    floatx4 y[8];
#pragma unroll
    for (int h2 = 0; h2 < 8; ++h2) y[h2] = (floatx4){0.f, 0.f, 0.f, 0.f};

    ushortx8 evc[2], evn[2];
    {   // prologue: load window 0's e-vectors (clamped)
        const int j0c = jstart + jj * 2;
        const int ja = min(j0c, jend - 1), jb2 = min(j0c + 1, jend - 1);
        evc[0] = *(const ushortx8*)(e16 + ebase + (size_t)(ja * 16 + i_p) * 8);
        evc[1] = *(const ushortx8*)(e16 + ebase + (size_t)(jb2 * 16 + i_p) * 8);
    }
    __syncthreads();

    for (int n = 0; n < nw; ++n) {
        const int jw0 = jstart + n * 32;
        {   // prefetch window n+1 (clamped; unused on last iter)
            const int j0n = jstart + (n + 1) * 32 + jj * 2;
            const int ja = min(j0n, jend - 1), jb2 = min(j0n + 1, jend - 1);
            evn[0] = *(const ushortx8*)(e16 + ebase + (size_t)(ja * 16 + i_p) * 8);
            evn[1] = *(const ushortx8*)(e16 + ebase + (size_t)(jb2 * 16 + i_p) * 8);
        }
        // postmix current window from registers
        float p2[2][8];
#pragma unroll
        for (int s = 0; s < 2; ++s) {
#pragma unroll
            for (int h2 = 0; h2 < 8; ++h2) p2[s][h2] = 0.f;
            const int j = jw0 + jj * 2 + s;
            if (j < jend) {
#pragma unroll
                for (int h1 = 0; h1 < 8; ++h1) {
                    const float e = __uint_as_float((unsigned int)(unsigned short)evc[s][h1] << 16)
                                    * linv[h1];
                    const float4 po0 = *(const float4*)(&post_s[h1 * 8]);
                    const float4 po1 = *(const float4*)(&post_s[h1 * 8 + 4]);
                    p2[s][0] = fmaf(e, po0.x, p2[s][0]);
                    p2[s][1] = fmaf(e, po0.y, p2[s][1]);
                    p2[s][2] = fmaf(e, po0.z, p2[s][2]);
                    p2[s][3] = fmaf(e, po0.w, p2[s][3]);
                    p2[s][4] = fmaf(e, po1.x, p2[s][4]);
                    p2[s][5] = fmaf(e, po1.y, p2[s][5]);
                    p2[s][6] = fmaf(e, po1.z, p2[s][6]);
                    p2[s][7] = fmaf(e, po1.w, p2[s][7]);
                }
            }
        }
        const int buf = n & 1;
#pragma unroll
        for (int h2 = 0; h2 < 8; ++h2)
            *(unsigned int*)(&p2s[buf][h2][i_p][jj * 2]) = pk2bf(p2[0][h2], p2[1][h2]);
        __syncthreads();   // single sync: writes(buf) done; reads of buf^1 from n-1 also done

        int jbv = jw0 + quad * 8;
        if (jbv > J - 8) jbv = J - 8;    // only masked cols; p2s=0 for them
#pragma unroll
        for (int h2 = 0; h2 < 8; ++h2) {
            const short8 aF = *(const short8*)(&p2s[buf][h2][iL][quad * 8]);
            const short8 bF = *(const short8*)(vt + ((size_t)(b * H + h2) * 64 + dW) * J + jbv);
            y[h2] = __builtin_amdgcn_mfma_f32_16x16x32_bf16(aF, bF, y[h2], 0, 0, 0);
        }
        evc[0] = evn[0]; evc[1] = evn[1];
    }

#pragma unroll
    for (int h2 = 0; h2 < 8; ++h2) {
#pragma unroll
        for (int r = 0; r < 4; ++r) {
            const int ii = i0 + quad * 4 + r;
            atomicAdd(ao + ((size_t)b * N + ii) * DIM + h2 * 64 + dW, y[h2][r]);
        }
    }
}

// ---------------- K3: output projection GEMM + bias (fp32 A inline-cvt) ---
__global__ __launch_bounds__(256)
void out_gemm(const float* __restrict__ ain, const unsigned short* __restrict__ WT,
              const float* __restrict__ bo, float* __restrict__ out)
{
    const int t = threadIdx.x;
    const int lane = t & 63, w = t >> 6;
    const int iL = lane & 15, quad = lane >> 4;
    const int mb = blockIdx.x * 64 + w * 16;
    const int n0 = blockIdx.y * 64;

    floatx4 acc[4];
#pragma unroll
    for (int ng = 0; ng < 4; ++ng) acc[ng] = (floatx4){0.f, 0.f, 0.f, 0.f};

    const float* arow = ain + (size_t)(mb + iL) * DIM + quad * 8;
#pragma unroll 4
    for (int k0 = 0; k0 < DIM; k0 += 32) {
        const float4 a0 = *(const float4*)(arow + k0);
        const float4 a1 = *(const float4*)(arow + k0 + 4);
        const short8 af = { (short)f2bf(a0.x), (short)f2bf(a0.y), (short)f2bf(a0.z), (short)f2bf(a0.w),
                            (short)f2bf(a1.x), (short)f2bf(a1.y), (short)f2bf(a1.z), (short)f2bf(a1.w) };
#pragma unroll
        for (int ng = 0; ng < 4; ++ng) {
            const short8 bf = *(const short8*)(WT + (size_t)(n0 + ng * 16 + iL) * DIM + k0 + quad * 8);
            acc[ng] = __builtin_amdgcn_mfma_f32_16x16x32_bf16(af, bf, acc[ng], 0, 0, 0);
        }
    }

#pragma unroll
    for (int ng = 0; ng < 4; ++ng) {
        const int n = n0 + ng * 16 + iL;
        const float bias = bo[n];
#pragma unroll
        for (int r = 0; r < 4; ++r) {
            const int m = mb + quad * 4 + r;
            out[(size_t)m * DIM + n] = acc[ng][r] + bias;
        }
    }
}

extern "C" void kernel_launch(void* const* d_in, const int* in_sizes, int n_in,
                              void* d_out, int out_size, void* d_ws, size_t ws_size,
                              hipStream_t stream)
{
    (void)in_sizes; (void)n_in; (void)out_size; (void)ws_size;
    const float* x      = (const float*)d_in[0];
    const float* Wq     = (const float*)d_in[1];
    const float* Wk     = (const float*)d_in[2];
    const float* Wv     = (const float*)d_in[3];
    const float* mem_k  = (const float*)d_in[4];
    const float* mem_v  = (const float*)d_in[5];
    const float* pre_p  = (const float*)d_in[6];
    const float* post_p = (const float*)d_in[7];
    const float* hs     = (const float*)d_in[8];
    const float* Wo     = (const float*)d_in[9];
    const float* bo     = (const float*)d_in[10];
    float* out = (float*)d_out;

    constexpr size_t NAO  = (size_t)B * N * DIM;        // 2,097,152 f32
    constexpr size_t NLB  = (size_t)B * 128 * H * 16;   //    32,768 f32
    constexpr size_t NW   = (size_t)DIM * DIM;          //   262,144 u16 each
    constexpr size_t NQ   = (size_t)B * H * N * 64;     // 2,097,152 u16
    constexpr size_t NK   = (size_t)B * H * J * 64;     // 2,113,536 u16
    // total ws usage ~= 92 MB (e-buffer 68.7 MB)

    float* ws = (float*)d_ws;
    float* ao   = ws;
    float* lbuf = ao + NAO;
    unsigned short* wtq  = (unsigned short*)(lbuf + NLB);
    unsigned short* wtk  = wtq + NW;
    unsigned short* wtv  = wtk + NW;
    unsigned short* wto  = wtv + NW;
    unsigned short* q16  = wto + NW;
    unsigned short* k16  = q16 + NQ;
    unsigned short* v16  = k16 + NK;
    unsigned short* e16  = v16 + NK;

    wt_conv<<<dim3(8, 8, 4), 256, 0, stream>>>(Wq, Wk, Wv, Wo, wtq, wtk, wtv, wto);
    qkv_gemm<<<dim3(64, 8, 3), 256, 0, stream>>>(x, wtq, wtk, wtv, q16, k16, v16);
    memkv_copy<<<dim3(32), 256, 0, stream>>>(mem_k, mem_v, k16, v16);
    hipMemsetAsync(ao, 0, (NAO + NLB) * sizeof(float), stream);
    attn_scores<<<dim3(CMAX, 128, B), 256, 0, stream>>>(q16, k16, pre_p, lbuf, e16);
    attn_pv2<<<dim3(CMAX, 128, B), 256, 0, stream>>>(e16, v16, post_p, hs, lbuf, ao);
    out_gemm<<<dim3(64, 8), 256, 0, stream>>>(ao, wto, bo, out);
}

// Round 10
// 298.277 us; speedup vs baseline: 5.4314x; 1.0105x over previous
//
#include <hip/hip_runtime.h>
#include <math.h>

namespace {
constexpr int B = 2;
constexpr int N = 2048;
constexpr int DIM = 512;
constexpr int H = 8;
constexpr int MEM = 16;
constexpr int J = MEM + N;       // 2064
constexpr int CHUNK = 256;
constexpr int CMAX = 9;          // ceil(2064/256)
constexpr float S2 = 0.125f * 1.4426950408889634f;  // SCALE * log2(e)
// e-buffer: per b, sum_t (16t+32) j-rows * 16 i * 8 h1 bf16 elems
constexpr size_t EPB = 17170432;        // 134144 * 128
}

typedef __attribute__((ext_vector_type(8))) short short8;
typedef __attribute__((ext_vector_type(4))) float floatx4;
typedef __attribute__((ext_vector_type(8))) unsigned short ushortx8;

__device__ inline unsigned short f2bf(float f) {
    unsigned int u = __float_as_uint(f);
    u += 0x7fffu + ((u >> 16) & 1u);   // RNE
    return (unsigned short)(u >> 16);
}
__device__ inline unsigned int pk2bf(float a, float b) {
    return ((__float_as_uint(a) + 0x8000u) >> 16) |
           ((__float_as_uint(b) + 0x8000u) & 0xffff0000u);
}

// ---------------- P1: W [k][n] fp32 -> WT [n][k] bf16 (4 matrices) --------
__global__ __launch_bounds__(256)
void wt_conv(const float* __restrict__ Wq, const float* __restrict__ Wk,
             const float* __restrict__ Wv, const float* __restrict__ Wo,
             unsigned short* __restrict__ tq, unsigned short* __restrict__ tk,
             unsigned short* __restrict__ tv, unsigned short* __restrict__ to_)
{
    const int z = blockIdx.z;
    const float* __restrict__ W = (z == 0) ? Wq : (z == 1) ? Wk : (z == 2) ? Wv : Wo;
    unsigned short* __restrict__ WT = (z == 0) ? tq : (z == 1) ? tk : (z == 2) ? tv : to_;
    const int k0 = blockIdx.x * 64, n0 = blockIdx.y * 64;

    __shared__ __align__(16) unsigned short tile[64][72];
    const int t = threadIdx.x;
    const int rrow = t >> 4, rcol = (t & 15) * 4;
#pragma unroll
    for (int rr = 0; rr < 4; ++rr) {
        const int row = rrow + rr * 16;
        const float4 v = *(const float4*)(W + (size_t)(k0 + row) * DIM + n0 + rcol);
        tile[rcol + 0][row] = f2bf(v.x);
        tile[rcol + 1][row] = f2bf(v.y);
        tile[rcol + 2][row] = f2bf(v.z);
        tile[rcol + 3][row] = f2bf(v.w);
    }
    __syncthreads();
    const int orow = t >> 2, oseg = (t & 3) * 16;
    *(ushortx8*)(WT + (size_t)(n0 + orow) * DIM + k0 + oseg) =
        *(const ushortx8*)(&tile[orow][oseg]);
    *(ushortx8*)(WT + (size_t)(n0 + orow) * DIM + k0 + oseg + 8) =
        *(const ushortx8*)(&tile[orow][oseg + 8]);
}

// ---------------- K1: QKV projection GEMM (3-slot register pipeline) ------
__global__ __launch_bounds__(256)
void qkv_gemm(const float* __restrict__ x, const unsigned short* __restrict__ tq,
              const unsigned short* __restrict__ tk, const unsigned short* __restrict__ tv,
              unsigned short* __restrict__ q16, unsigned short* __restrict__ k16,
              unsigned short* __restrict__ vt16)
{
    const int which = blockIdx.z;
    const unsigned short* __restrict__ WT = (which == 0) ? tq : (which == 1) ? tk : tv;
    const int t = threadIdx.x;
    const int lane = t & 63, w = t >> 6;
    const int iL = lane & 15, quad = lane >> 4;
    const int mb = blockIdx.x * 64 + w * 16;
    const int n0 = blockIdx.y * 64;

    floatx4 acc[4];
#pragma unroll
    for (int ng = 0; ng < 4; ++ng) acc[ng] = (floatx4){0.f, 0.f, 0.f, 0.f};

    const float* arow = x + (size_t)(mb + iL) * DIM + quad * 8;
    const unsigned short* brow = WT + (size_t)(n0 + iL) * DIM + quad * 8;

    float4 a0s[3], a1s[3];
    short8 bs[3][4];
#pragma unroll
    for (int s = 0; s < 2; ++s) {
        const int k0 = s * 32;
        a0s[s] = *(const float4*)(arow + k0);
        a1s[s] = *(const float4*)(arow + k0 + 4);
#pragma unroll
        for (int ng = 0; ng < 4; ++ng)
            bs[s][ng] = *(const short8*)(brow + (size_t)ng * 16 * DIM + k0);
    }
#pragma unroll
    for (int it = 0; it < 16; ++it) {
        const int cur = it % 3;
        if (it + 2 < 16) {
            const int nxt = (it + 2) % 3;
            const int k0 = (it + 2) * 32;
            a0s[nxt] = *(const float4*)(arow + k0);
            a1s[nxt] = *(const float4*)(arow + k0 + 4);
#pragma unroll
            for (int ng = 0; ng < 4; ++ng)
                bs[nxt][ng] = *(const short8*)(brow + (size_t)ng * 16 * DIM + k0);
        }
        const float4 a0 = a0s[cur], a1 = a1s[cur];
        const short8 af = { (short)f2bf(a0.x), (short)f2bf(a0.y), (short)f2bf(a0.z), (short)f2bf(a0.w),
                            (short)f2bf(a1.x), (short)f2bf(a1.y), (short)f2bf(a1.z), (short)f2bf(a1.w) };
#pragma unroll
        for (int ng = 0; ng < 4; ++ng)
            acc[ng] = __builtin_amdgcn_mfma_f32_16x16x32_bf16(af, bs[cur][ng], acc[ng], 0, 0, 0);
    }

    const int h0 = n0 >> 6;
    if (which == 2) {
#pragma unroll
        for (int ng = 0; ng < 4; ++ng) {
            const int d = ng * 16 + iL;
#pragma unroll
            for (int r = 0; r < 4; ++r) {
                const int m = mb + quad * 4 + r;
                const int bb = m >> 11, ii = m & (N - 1);
                vt16[((size_t)(bb * H + h0) * 64 + d) * J + MEM + ii] = f2bf(acc[ng][r]);
            }
        }
    } else {
        unsigned short* dst = (which == 0) ? q16 : k16;
#pragma unroll
        for (int ng = 0; ng < 4; ++ng) {
            const int d = ng * 16 + iL;
#pragma unroll
            for (int r = 0; r < 4; ++r) {
                const int m = mb + quad * 4 + r;
                const int bb = m >> 11, ii = m & (N - 1);
                const size_t rowbase = (which == 0)
                    ? ((size_t)(bb * H + h0) * N + ii)
                    : ((size_t)(bb * H + h0) * J + MEM + ii);
                dst[rowbase * 64 + d] = f2bf(acc[ng][r]);
            }
        }
    }
}

// ---------------- K1b: mem_k/mem_v into k16 rows / vt16 cols 0..15 --------
__global__ void memkv_copy(const float* __restrict__ mem_k, const float* __restrict__ mem_v,
                           unsigned short* __restrict__ k16, unsigned short* __restrict__ vt16)
{
    const int idx = blockIdx.x * 256 + threadIdx.x;  // H*MEM*64 = 8192
    if (idx >= H * MEM * 64) return;
    const int h0 = idx >> 10;
    const int rd = idx & 1023;
    const int r = rd >> 6, d = rd & 63;
    const unsigned short kk = f2bf(mem_k[idx]);
    const unsigned short vv = f2bf(mem_v[idx]);
#pragma unroll
    for (int bb = 0; bb < B; ++bb) {
        k16[((size_t)(bb * H + h0) * J + r) * 64 + d] = kk;
        vt16[((size_t)(bb * H + h0) * 64 + d) * J + r] = vv;
    }
}

// ---------------- K2a: scores pass — QK + premix + exp; store e; sum l ----
// q-tile staged in LDS; k fragments prefetched one h0 ahead.
__global__ __launch_bounds__(256)
void attn_scores(const unsigned short* __restrict__ qb, const unsigned short* __restrict__ kb,
                 const float* __restrict__ prep, float* __restrict__ lbuf,
                 unsigned short* __restrict__ e16)
{
    const int c = blockIdx.x, tt = 127 - blockIdx.y, b = blockIdx.z;
    const int i0 = tt * 16;
    const int jlim = i0 + 32;            // == min(J, i0+32) for all tt
    const int jstart = c * CHUNK;
    if (jstart >= jlim) return;
    const int jend = min(jstart + CHUNK, jlim);

    __shared__ __align__(16) unsigned short q_s[8][16][64];  // 16 KB
    __shared__ __align__(16) float pre_s[64];
    const int t = threadIdx.x;
    if (t < 64) pre_s[t] = prep[t];
    // cooperative q-tile load: 8192 u16, 8 per thread per iter
#pragma unroll
    for (int u4 = 0; u4 < 4; ++u4) {
        const int u = t + u4 * 256;          // over 1024 groups of 8
        const int h = u >> 7, rem = u & 127, i = rem >> 3, seg = (rem & 7) * 8;
        *(ushortx8*)(&q_s[h][i][seg]) =
            *(const ushortx8*)(qb + ((size_t)(b * H + h) * N + i0 + i) * 64 + seg);
    }
    __syncthreads();

    const int lane = t & 63, w = t >> 6;
    const int iL = lane & 15, quad = lane >> 4;
    const int i = i0 + iL;
    const size_t ebase = (size_t)b * EPB + (size_t)(8 * tt * tt + 24 * tt) * 128;

    float l_acc[8];
#pragma unroll
    for (int h1 = 0; h1 < 8; ++h1) l_acc[h1] = 0.f;

    bool any = false;
    for (int j0 = jstart + w * 16; j0 < jend; j0 += 64) {
        any = true;
        float dots[8][4];
#pragma unroll
        for (int h1 = 0; h1 < 8; ++h1)
#pragma unroll
            for (int r = 0; r < 4; ++r) dots[h1][r] = 0.f;

        // k prefetch chain over h0
        const unsigned short* kp0 = kb + ((size_t)(b * H) * J + j0 + iL) * 64 + quad * 8;
        short8 kc0 = *(const short8*)kp0;
        short8 kc1 = *(const short8*)(kp0 + 32);
#pragma unroll
        for (int h0 = 0; h0 < 8; ++h0) {
            short8 kn0, kn1;
            if (h0 < 7) {
                const unsigned short* kpn =
                    kb + ((size_t)(b * H + h0 + 1) * J + j0 + iL) * 64 + quad * 8;
                kn0 = *(const short8*)kpn;
                kn1 = *(const short8*)(kpn + 32);
            }
            const short8 qf0 = *(const short8*)(&q_s[h0][iL][quad * 8]);
            const short8 qf1 = *(const short8*)(&q_s[h0][iL][quad * 8 + 32]);
            floatx4 a = {0.f, 0.f, 0.f, 0.f};
            a = __builtin_amdgcn_mfma_f32_16x16x32_bf16(kc0, qf0, a, 0, 0, 0);
            a = __builtin_amdgcn_mfma_f32_16x16x32_bf16(kc1, qf1, a, 0, 0, 0);
            const float4 pr0 = *(const float4*)(&pre_s[h0 * 8]);
            const float4 pr1 = *(const float4*)(&pre_s[h0 * 8 + 4]);
#pragma unroll
            for (int r = 0; r < 4; ++r) {
                const float av = a[r];
                dots[0][r] = fmaf(av, pr0.x, dots[0][r]);
                dots[1][r] = fmaf(av, pr0.y, dots[1][r]);
                dots[2][r] = fmaf(av, pr0.z, dots[2][r]);
                dots[3][r] = fmaf(av, pr0.w, dots[3][r]);
                dots[4][r] = fmaf(av, pr1.x, dots[4][r]);
                dots[5][r] = fmaf(av, pr1.y, dots[5][r]);
                dots[6][r] = fmaf(av, pr1.z, dots[6][r]);
                dots[7][r] = fmaf(av, pr1.w, dots[7][r]);
            }
            kc0 = kn0; kc1 = kn1;
        }

        unsigned int epk[4][4];
        float etmp[4];
#pragma unroll
        for (int h1 = 0; h1 < 8; ++h1) {
            const float slopeE = 1.4426950408889634f / (float)(2 << h1);
#pragma unroll
            for (int r = 0; r < 4; ++r) {
                const int j = j0 + quad * 4 + r;
                const bool vis = (j - MEM) <= i;
                const float e = vis ? exp2f(fmaf(dots[h1][r], S2, slopeE * (float)(j - i - MEM)))
                                    : 0.f;
                l_acc[h1] += e;
                if (h1 & 1) epk[r][h1 >> 1] = pk2bf(etmp[r], e);
                else        etmp[r] = e;
            }
        }
#pragma unroll
        for (int r = 0; r < 4; ++r) {
            uint4 o = make_uint4(epk[r][0], epk[r][1], epk[r][2], epk[r][3]);
            *(uint4*)(e16 + ebase + (size_t)((j0 + quad * 4 + r) * 16 + iL) * 8) = o;
        }
    }

#pragma unroll
    for (int h1 = 0; h1 < 8; ++h1) {
        float v = l_acc[h1];
        v += __shfl_xor(v, 16);
        v += __shfl_xor(v, 32);
        if (quad == 0 && any)
            atomicAdd(lbuf + ((size_t)(b * 128 + tt) * 8 + h1) * 16 + iL, v);
    }
}

// ---------------- K2b: pv pass — pipelined e-load, dbuf LDS, PV-MFMA ------
__global__ __launch_bounds__(256)
void attn_pv2(const unsigned short* __restrict__ e16, const unsigned short* __restrict__ vt,
              const float* __restrict__ postp, const float* __restrict__ hsp,
              const float* __restrict__ lbuf, float* __restrict__ ao)
{
    const int c = blockIdx.x, tt = 127 - blockIdx.y, b = blockIdx.z;
    const int i0 = tt * 16;
    const int jlim = i0 + 32;
    const int jstart = c * CHUNK;
    if (jstart >= jlim) return;
    const int jend = min(jstart + CHUNK, jlim);
    const int nw = (jend - jstart + 31) >> 5;   // 32-j windows (<=8)

    __shared__ __align__(16) unsigned short p2s[2][8][16][40];  // double buffer
    __shared__ __align__(16) float post_s[64];

    const int t = threadIdx.x;
    if (t < 64) post_s[t] = postp[t] * hsp[t & 7];

    const int lane = t & 63, w = t >> 6;
    const int iL = lane & 15, quad = lane >> 4;
    const int dW = w * 16 + iL;          // consumer d
    const int i_p = t & 15;              // producer i
    const int jj = t >> 4;               // producer j-group (0..15)
    const size_t ebase = (size_t)b * EPB + (size_t)(8 * tt * tt + 24 * tt) * 128;

    float linv[8];
#pragma unroll
    for (int h1 = 0; h1 < 8; ++h1)
        linv[h1] = 1.0f / lbuf[((size_t)(b * 128 + tt) * 8 + h1) * 16 + i_p];

    floatx4 y[8];
#pragma unroll
    for (int h2 = 0; h2 < 8; ++h2) y[h2] = (floatx4){0.f, 0.f, 0.f, 0.f};

    ushortx8 evc[2], evn[2];
    {   // prologue: load window 0's e-vectors (clamped)
        const int j0c = jstart + jj * 2;
        const int ja = min(j0c, jend - 1), jb2 = min(j0c + 1, jend - 1);
        evc[0] = *(const ushortx8*)(e16 + ebase + (size_t)(ja * 16 + i_p) * 8);
        evc[1] = *(const ushortx8*)(e16 + ebase + (size_t)(jb2 * 16 + i_p) * 8);
    }
    __syncthreads();

    for (int n = 0; n < nw; ++n) {
        const int jw0 = jstart + n * 32;
        {   // prefetch window n+1 (clamped; unused on last iter)
            const int j0n = jstart + (n + 1) * 32 + jj * 2;
            const int ja = min(j0n, jend - 1), jb2 = min(j0n + 1, jend - 1);
            evn[0] = *(const ushortx8*)(e16 + ebase + (size_t)(ja * 16 + i_p) * 8);
            evn[1] = *(const ushortx8*)(e16 + ebase + (size_t)(jb2 * 16 + i_p) * 8);
        }
        // postmix current window from registers
        float p2[2][8];
#pragma unroll
        for (int s = 0; s < 2; ++s) {
#pragma unroll
            for (int h2 = 0; h2 < 8; ++h2) p2[s][h2] = 0.f;
            const int j = jw0 + jj * 2 + s;
            if (j < jend) {
#pragma unroll
                for (int h1 = 0; h1 < 8; ++h1) {
                    const float e = __uint_as_float((unsigned int)(unsigned short)evc[s][h1] << 16)
                                    * linv[h1];
                    const float4 po0 = *(const float4*)(&post_s[h1 * 8]);
                    const float4 po1 = *(const float4*)(&post_s[h1 * 8 + 4]);
                    p2[s][0] = fmaf(e, po0.x, p2[s][0]);
                    p2[s][1] = fmaf(e, po0.y, p2[s][1]);
                    p2[s][2] = fmaf(e, po0.z, p2[s][2]);
                    p2[s][3] = fmaf(e, po0.w, p2[s][3]);
                    p2[s][4] = fmaf(e, po1.x, p2[s][4]);
                    p2[s][5] = fmaf(e, po1.y, p2[s][5]);
                    p2[s][6] = fmaf(e, po1.z, p2[s][6]);
                    p2[s][7] = fmaf(e, po1.w, p2[s][7]);
                }
            }
        }
        const int buf = n & 1;
#pragma unroll
        for (int h2 = 0; h2 < 8; ++h2)
            *(unsigned int*)(&p2s[buf][h2][i_p][jj * 2]) = pk2bf(p2[0][h2], p2[1][h2]);
        __syncthreads();   // single sync: writes(buf) done; reads of buf^1 from n-1 also done

        int jbv = jw0 + quad * 8;
        if (jbv > J - 8) jbv = J - 8;    // only masked cols; p2s=0 for them
#pragma unroll
        for (int h2 = 0; h2 < 8; ++h2) {
            const short8 aF = *(const short8*)(&p2s[buf][h2][iL][quad * 8]);
            const short8 bF = *(const short8*)(vt + ((size_t)(b * H + h2) * 64 + dW) * J + jbv);
            y[h2] = __builtin_amdgcn_mfma_f32_16x16x32_bf16(aF, bF, y[h2], 0, 0, 0);
        }
        evc[0] = evn[0]; evc[1] = evn[1];
    }

#pragma unroll
    for (int h2 = 0; h2 < 8; ++h2) {
#pragma unroll
        for (int r = 0; r < 4; ++r) {
            const int ii = i0 + quad * 4 + r;
            atomicAdd(ao + ((size_t)b * N + ii) * DIM + h2 * 64 + dW, y[h2][r]);
        }
    }
}

// ---------------- K3: output projection GEMM + bias (3-slot pipeline) -----
__global__ __launch_bounds__(256)
void out_gemm(const float* __restrict__ ain, const unsigned short* __restrict__ WT,
              const float* __restrict__ bo, float* __restrict__ out)
{
    const int t = threadIdx.x;
    const int lane = t & 63, w = t >> 6;
    const int iL = lane & 15, quad = lane >> 4;
    const int mb = blockIdx.x * 64 + w * 16;
    const int n0 = blockIdx.y * 64;

    floatx4 acc[4];
#pragma unroll
    for (int ng = 0; ng < 4; ++ng) acc[ng] = (floatx4){0.f, 0.f, 0.f, 0.f};

    const float* arow = ain + (size_t)(mb + iL) * DIM + quad * 8;
    const unsigned short* brow = WT + (size_t)(n0 + iL) * DIM + quad * 8;

    float4 a0s[3], a1s[3];
    short8 bs[3][4];
#pragma unroll
    for (int s = 0; s < 2; ++s) {
        const int k0 = s * 32;
        a0s[s] = *(const float4*)(arow + k0);
        a1s[s] = *(const float4*)(arow + k0 + 4);
#pragma unroll
        for (int ng = 0; ng < 4; ++ng)
            bs[s][ng] = *(const short8*)(brow + (size_t)ng * 16 * DIM + k0);
    }
#pragma unroll
    for (int it = 0; it < 16; ++it) {
        const int cur = it % 3;
        if (it + 2 < 16) {
            const int nxt = (it + 2) % 3;
            const int k0 = (it + 2) * 32;
            a0s[nxt] = *(const float4*)(arow + k0);
            a1s[nxt] = *(const float4*)(arow + k0 + 4);
#pragma unroll
            for (int ng = 0; ng < 4; ++ng)
                bs[nxt][ng] = *(const short8*)(brow + (size_t)ng * 16 * DIM + k0);
        }
        const float4 a0 = a0s[cur], a1 = a1s[cur];
        const short8 af = { (short)f2bf(a0.x), (short)f2bf(a0.y), (short)f2bf(a0.z), (short)f2bf(a0.w),
                            (short)f2bf(a1.x), (short)f2bf(a1.y), (short)f2bf(a1.z), (short)f2bf(a1.w) };
#pragma unroll
        for (int ng = 0; ng < 4; ++ng)
            acc[ng] = __builtin_amdgcn_mfma_f32_16x16x32_bf16(af, bs[cur][ng], acc[ng], 0, 0, 0);
    }

#pragma unroll
    for (int ng = 0; ng < 4; ++ng) {
        const int n = n0 + ng * 16 + iL;
        const float bias = bo[n];
#pragma unroll
        for (int r = 0; r < 4; ++r) {
            const int m = mb + quad * 4 + r;
            out[(size_t)m * DIM + n] = acc[ng][r] + bias;
        }
    }
}

extern "C" void kernel_launch(void* const* d_in, const int* in_sizes, int n_in,
                              void* d_out, int out_size, void* d_ws, size_t ws_size,
                              hipStream_t stream)
{
    (void)in_sizes; (void)n_in; (void)out_size; (void)ws_size;
    const float* x      = (const float*)d_in[0];
    const float* Wq     = (const float*)d_in[1];
    const float* Wk     = (const float*)d_in[2];
    const float* Wv     = (const float*)d_in[3];
    const float* mem_k  = (const float*)d_in[4];
    const float* mem_v  = (const float*)d_in[5];
    const float* pre_p  = (const float*)d_in[6];
    const float* post_p = (const float*)d_in[7];
    const float* hs     = (const float*)d_in[8];
    const float* Wo     = (const float*)d_in[9];
    const float* bo     = (const float*)d_in[10];
    float* out = (float*)d_out;

    constexpr size_t NAO  = (size_t)B * N * DIM;        // 2,097,152 f32
    constexpr size_t NLB  = (size_t)B * 128 * H * 16;   //    32,768 f32
    constexpr size_t NW   = (size_t)DIM * DIM;          //   262,144 u16 each
    constexpr size_t NQ   = (size_t)B * H * N * 64;     // 2,097,152 u16
    constexpr size_t NK   = (size_t)B * H * J * 64;     // 2,113,536 u16
    // total ws usage ~= 92 MB (e-buffer 68.7 MB)

    float* ws = (float*)d_ws;
    float* ao   = ws;
    float* lbuf = ao + NAO;
    unsigned short* wtq  = (unsigned short*)(lbuf + NLB);
    unsigned short* wtk  = wtq + NW;
    unsigned short* wtv  = wtk + NW;
    unsigned short* wto  = wtv + NW;
    unsigned short* q16  = wto + NW;
    unsigned short* k16  = q16 + NQ;
    unsigned short* v16  = k16 + NK;
    unsigned short* e16  = v16 + NK;

    wt_conv<<<dim3(8, 8, 4), 256, 0, stream>>>(Wq, Wk, Wv, Wo, wtq, wtk, wtv, wto);
    qkv_gemm<<<dim3(64, 8, 3), 256, 0, stream>>>(x, wtq, wtk, wtv, q16, k16, v16);
    memkv_copy<<<dim3(32), 256, 0, stream>>>(mem_k, mem_v, k16, v16);
    hipMemsetAsync(ao, 0, (NAO + NLB) * sizeof(float), stream);
    attn_scores<<<dim3(CMAX, 128, B), 256, 0, stream>>>(q16, k16, pre_p, lbuf, e16);
    attn_pv2<<<dim3(CMAX, 128, B), 256, 0, stream>>>(e16, v16, post_p, hs, lbuf, ao);
    out_gemm<<<dim3(64, 8), 256, 0, stream>>>(ao, wto, bo, out);
}

// Round 11
// 237.827 us; speedup vs baseline: 6.8119x; 1.2542x over previous
//
#include <hip/hip_runtime.h>
#include <math.h>

namespace {
constexpr int B = 2;
constexpr int N = 2048;
constexpr int DIM = 512;
constexpr int H = 8;
constexpr int MEM = 16;
constexpr int J = MEM + N;       // 2064
constexpr int CHUNK = 256;
constexpr int CMAX = 9;          // ceil(2064/256)
constexpr float S2 = 0.125f * 1.4426950408889634f;  // SCALE * log2(e)
// e-buffer: per b, sum_t (16t+32) j-rows * 16 i * 8 h1 bf16 elems
constexpr size_t EPB = 17170432;        // 134144 * 128
}

typedef __attribute__((ext_vector_type(8))) short short8;
typedef __attribute__((ext_vector_type(4))) float floatx4;
typedef __attribute__((ext_vector_type(4))) unsigned short ushortx4;
typedef __attribute__((ext_vector_type(8))) unsigned short ushortx8;

__device__ inline unsigned short f2bf(float f) {
    unsigned int u = __float_as_uint(f);
    u += 0x7fffu + ((u >> 16) & 1u);   // RNE
    return (unsigned short)(u >> 16);
}
__device__ inline unsigned int pk2bf(float a, float b) {
    return ((__float_as_uint(a) + 0x8000u) >> 16) |
           ((__float_as_uint(b) + 0x8000u) & 0xffff0000u);
}

// ---------------- P1: W [k][n] fp32 -> WT [n][k] bf16 (4 matrices) --------
__global__ __launch_bounds__(256)
void wt_conv(const float* __restrict__ Wq, const float* __restrict__ Wk,
             const float* __restrict__ Wv, const float* __restrict__ Wo,
             unsigned short* __restrict__ tq, unsigned short* __restrict__ tk,
             unsigned short* __restrict__ tv, unsigned short* __restrict__ to_)
{
    const int z = blockIdx.z;
    const float* __restrict__ W = (z == 0) ? Wq : (z == 1) ? Wk : (z == 2) ? Wv : Wo;
    unsigned short* __restrict__ WT = (z == 0) ? tq : (z == 1) ? tk : (z == 2) ? tv : to_;
    const int k0 = blockIdx.x * 64, n0 = blockIdx.y * 64;

    __shared__ __align__(16) unsigned short tile[64][72];
    const int t = threadIdx.x;
    const int rrow = t >> 4, rcol = (t & 15) * 4;
#pragma unroll
    for (int rr = 0; rr < 4; ++rr) {
        const int row = rrow + rr * 16;
        const float4 v = *(const float4*)(W + (size_t)(k0 + row) * DIM + n0 + rcol);
        tile[rcol + 0][row] = f2bf(v.x);
        tile[rcol + 1][row] = f2bf(v.y);
        tile[rcol + 2][row] = f2bf(v.z);
        tile[rcol + 3][row] = f2bf(v.w);
    }
    __syncthreads();
    const int orow = t >> 2, oseg = (t & 3) * 16;
    *(ushortx8*)(WT + (size_t)(n0 + orow) * DIM + k0 + oseg) =
        *(const ushortx8*)(&tile[orow][oseg]);
    *(ushortx8*)(WT + (size_t)(n0 + orow) * DIM + k0 + oseg + 8) =
        *(const ushortx8*)(&tile[orow][oseg + 8]);
}

// ---------------- K1: QKV projection GEMM (LDS double-buffered, bf16 MFMA)
__global__ __launch_bounds__(256)
void qkv_gemm(const float* __restrict__ x, const unsigned short* __restrict__ tq,
              const unsigned short* __restrict__ tk, const unsigned short* __restrict__ tv,
              unsigned short* __restrict__ q16, unsigned short* __restrict__ k16,
              unsigned short* __restrict__ vt16)
{
    const int which = blockIdx.z;
    const unsigned short* __restrict__ WT = (which == 0) ? tq : (which == 1) ? tk : tv;
    const int t = threadIdx.x;
    const int lane = t & 63, w = t >> 6;
    const int iL = lane & 15, quad = lane >> 4;
    const int mb = blockIdx.x * 64;
    const int n0 = blockIdx.y * 64;

    __shared__ __align__(16) unsigned short As[2][64][32];  // 8 KB
    __shared__ __align__(16) unsigned short Bs[2][64][32];  // 8 KB

    // staging coords (coalesced: consecutive t -> consecutive addresses)
    const int ar0 = t >> 3, as4 = (t & 7) * 4;        // A: 2 segs/thread (u and u+256)
    const int br0 = t >> 2, bs8 = (t & 3) * 8;        // B: 1 seg/thread

    floatx4 acc[4];
#pragma unroll
    for (int ng = 0; ng < 4; ++ng) acc[ng] = (floatx4){0.f, 0.f, 0.f, 0.f};

    // prologue: stage k0=0 into buf 0
    {
        const float4 v0 = *(const float4*)(x + (size_t)(mb + ar0) * DIM + as4);
        const float4 v1 = *(const float4*)(x + (size_t)(mb + ar0 + 32) * DIM + as4);
        ushortx4 o0 = { f2bf(v0.x), f2bf(v0.y), f2bf(v0.z), f2bf(v0.w) };
        ushortx4 o1 = { f2bf(v1.x), f2bf(v1.y), f2bf(v1.z), f2bf(v1.w) };
        *(ushortx4*)(&As[0][ar0][as4]) = o0;
        *(ushortx4*)(&As[0][ar0 + 32][as4]) = o1;
        *(ushortx8*)(&Bs[0][br0][bs8]) =
            *(const ushortx8*)(WT + (size_t)(n0 + br0) * DIM + bs8);
    }
    __syncthreads();

#pragma unroll
    for (int it = 0; it < 16; ++it) {
        const int buf = it & 1;
        if (it + 1 < 16) {
            const int k0 = (it + 1) * 32;
            const float4 v0 = *(const float4*)(x + (size_t)(mb + ar0) * DIM + k0 + as4);
            const float4 v1 = *(const float4*)(x + (size_t)(mb + ar0 + 32) * DIM + k0 + as4);
            const ushortx8 bv =
                *(const ushortx8*)(WT + (size_t)(n0 + br0) * DIM + k0 + bs8);
            ushortx4 o0 = { f2bf(v0.x), f2bf(v0.y), f2bf(v0.z), f2bf(v0.w) };
            ushortx4 o1 = { f2bf(v1.x), f2bf(v1.y), f2bf(v1.z), f2bf(v1.w) };
            *(ushortx4*)(&As[buf ^ 1][ar0][as4]) = o0;
            *(ushortx4*)(&As[buf ^ 1][ar0 + 32][as4]) = o1;
            *(ushortx8*)(&Bs[buf ^ 1][br0][bs8]) = bv;
        }
        const short8 af = *(const short8*)(&As[buf][w * 16 + iL][quad * 8]);
#pragma unroll
        for (int ng = 0; ng < 4; ++ng) {
            const short8 bf = *(const short8*)(&Bs[buf][ng * 16 + iL][quad * 8]);
            acc[ng] = __builtin_amdgcn_mfma_f32_16x16x32_bf16(af, bf, acc[ng], 0, 0, 0);
        }
        __syncthreads();  // staging writes (buf^1) done + all reads of buf done
    }

    const int mbw = mb + w * 16;
    const int h0 = n0 >> 6;
    if (which == 2) {
#pragma unroll
        for (int ng = 0; ng < 4; ++ng) {
            const int d = ng * 16 + iL;
#pragma unroll
            for (int r = 0; r < 4; ++r) {
                const int m = mbw + quad * 4 + r;
                const int bb = m >> 11, ii = m & (N - 1);
                vt16[((size_t)(bb * H + h0) * 64 + d) * J + MEM + ii] = f2bf(acc[ng][r]);
            }
        }
    } else {
        unsigned short* dst = (which == 0) ? q16 : k16;
#pragma unroll
        for (int ng = 0; ng < 4; ++ng) {
            const int d = ng * 16 + iL;
#pragma unroll
            for (int r = 0; r < 4; ++r) {
                const int m = mbw + quad * 4 + r;
                const int bb = m >> 11, ii = m & (N - 1);
                const size_t rowbase = (which == 0)
                    ? ((size_t)(bb * H + h0) * N + ii)
                    : ((size_t)(bb * H + h0) * J + MEM + ii);
                dst[rowbase * 64 + d] = f2bf(acc[ng][r]);
            }
        }
    }
}

// ---------------- K1b: mem_k/mem_v into k16 rows / vt16 cols 0..15 --------
__global__ void memkv_copy(const float* __restrict__ mem_k, const float* __restrict__ mem_v,
                           unsigned short* __restrict__ k16, unsigned short* __restrict__ vt16)
{
    const int idx = blockIdx.x * 256 + threadIdx.x;  // H*MEM*64 = 8192
    if (idx >= H * MEM * 64) return;
    const int h0 = idx >> 10;
    const int rd = idx & 1023;
    const int r = rd >> 6, d = rd & 63;
    const unsigned short kk = f2bf(mem_k[idx]);
    const unsigned short vv = f2bf(mem_v[idx]);
#pragma unroll
    for (int bb = 0; bb < B; ++bb) {
        k16[((size_t)(bb * H + h0) * J + r) * 64 + d] = kk;
        vt16[((size_t)(bb * H + h0) * 64 + d) * J + r] = vv;
    }
}

// ---------------- K2a: scores pass — QK + premix + exp; store e; sum l ----
// q-tile staged in LDS; k fragments prefetched one h0 ahead.
__global__ __launch_bounds__(256)
void attn_scores(const unsigned short* __restrict__ qb, const unsigned short* __restrict__ kb,
                 const float* __restrict__ prep, float* __restrict__ lbuf,
                 unsigned short* __restrict__ e16)
{
    const int c = blockIdx.x, tt = 127 - blockIdx.y, b = blockIdx.z;
    const int i0 = tt * 16;
    const int jlim = i0 + 32;            // == min(J, i0+32) for all tt
    const int jstart = c * CHUNK;
    if (jstart >= jlim) return;
    const int jend = min(jstart + CHUNK, jlim);

    __shared__ __align__(16) unsigned short q_s[8][16][64];  // 16 KB
    __shared__ __align__(16) float pre_s[64];
    const int t = threadIdx.x;
    if (t < 64) pre_s[t] = prep[t];
    // cooperative q-tile load: 8192 u16, 8 per thread per iter
#pragma unroll
    for (int u4 = 0; u4 < 4; ++u4) {
        const int u = t + u4 * 256;          // over 1024 groups of 8
        const int h = u >> 7, rem = u & 127, i = rem >> 3, seg = (rem & 7) * 8;
        *(ushortx8*)(&q_s[h][i][seg]) =
            *(const ushortx8*)(qb + ((size_t)(b * H + h) * N + i0 + i) * 64 + seg);
    }
    __syncthreads();

    const int lane = t & 63, w = t >> 6;
    const int iL = lane & 15, quad = lane >> 4;
    const int i = i0 + iL;
    const size_t ebase = (size_t)b * EPB + (size_t)(8 * tt * tt + 24 * tt) * 128;

    float l_acc[8];
#pragma unroll
    for (int h1 = 0; h1 < 8; ++h1) l_acc[h1] = 0.f;

    bool any = false;
    for (int j0 = jstart + w * 16; j0 < jend; j0 += 64) {
        any = true;
        float dots[8][4];
#pragma unroll
        for (int h1 = 0; h1 < 8; ++h1)
#pragma unroll
            for (int r = 0; r < 4; ++r) dots[h1][r] = 0.f;

        // k prefetch chain over h0
        const unsigned short* kp0 = kb + ((size_t)(b * H) * J + j0 + iL) * 64 + quad * 8;
        short8 kc0 = *(const short8*)kp0;
        short8 kc1 = *(const short8*)(kp0 + 32);
#pragma unroll
        for (int h0 = 0; h0 < 8; ++h0) {
            short8 kn0, kn1;
            if (h0 < 7) {
                const unsigned short* kpn =
                    kb + ((size_t)(b * H + h0 + 1) * J + j0 + iL) * 64 + quad * 8;
                kn0 = *(const short8*)kpn;
                kn1 = *(const short8*)(kpn + 32);
            }
            const short8 qf0 = *(const short8*)(&q_s[h0][iL][quad * 8]);
            const short8 qf1 = *(const short8*)(&q_s[h0][iL][quad * 8 + 32]);
            floatx4 a = {0.f, 0.f, 0.f, 0.f};
            a = __builtin_amdgcn_mfma_f32_16x16x32_bf16(kc0, qf0, a, 0, 0, 0);
            a = __builtin_amdgcn_mfma_f32_16x16x32_bf16(kc1, qf1, a, 0, 0, 0);
            const float4 pr0 = *(const float4*)(&pre_s[h0 * 8]);
            const float4 pr1 = *(const float4*)(&pre_s[h0 * 8 + 4]);
#pragma unroll
            for (int r = 0; r < 4; ++r) {
                const float av = a[r];
                dots[0][r] = fmaf(av, pr0.x, dots[0][r]);
                dots[1][r] = fmaf(av, pr0.y, dots[1][r]);
                dots[2][r] = fmaf(av, pr0.z, dots[2][r]);
                dots[3][r] = fmaf(av, pr0.w, dots[3][r]);
                dots[4][r] = fmaf(av, pr1.x, dots[4][r]);
                dots[5][r] = fmaf(av, pr1.y, dots[5][r]);
                dots[6][r] = fmaf(av, pr1.z, dots[6][r]);
                dots[7][r] = fmaf(av, pr1.w, dots[7][r]);
            }
            kc0 = kn0; kc1 = kn1;
        }

        unsigned int epk[4][4];
        float etmp[4];
#pragma unroll
        for (int h1 = 0; h1 < 8; ++h1) {
            const float slopeE = 1.4426950408889634f / (float)(2 << h1);
#pragma unroll
            for (int r = 0; r < 4; ++r) {
                const int j = j0 + quad * 4 + r;
                const bool vis = (j - MEM) <= i;
                const float e = vis ? exp2f(fmaf(dots[h1][r], S2, slopeE * (float)(j - i - MEM)))
                                    : 0.f;
                l_acc[h1] += e;
                if (h1 & 1) epk[r][h1 >> 1] = pk2bf(etmp[r], e);
                else        etmp[r] = e;
            }
        }
#pragma unroll
        for (int r = 0; r < 4; ++r) {
            uint4 o = make_uint4(epk[r][0], epk[r][1], epk[r][2], epk[r][3]);
            *(uint4*)(e16 + ebase + (size_t)((j0 + quad * 4 + r) * 16 + iL) * 8) = o;
        }
    }

#pragma unroll
    for (int h1 = 0; h1 < 8; ++h1) {
        float v = l_acc[h1];
        v += __shfl_xor(v, 16);
        v += __shfl_xor(v, 32);
        if (quad == 0 && any)
            atomicAdd(lbuf + ((size_t)(b * 128 + tt) * 8 + h1) * 16 + iL, v);
    }
}

// ---------------- K2b: pv pass — pipelined e-load, dbuf LDS, PV-MFMA ------
__global__ __launch_bounds__(256)
void attn_pv2(const unsigned short* __restrict__ e16, const unsigned short* __restrict__ vt,
              const float* __restrict__ postp, const float* __restrict__ hsp,
              const float* __restrict__ lbuf, float* __restrict__ ao)
{
    const int c = blockIdx.x, tt = 127 - blockIdx.y, b = blockIdx.z;
    const int i0 = tt * 16;
    const int jlim = i0 + 32;
    const int jstart = c * CHUNK;
    if (jstart >= jlim) return;
    const int jend = min(jstart + CHUNK, jlim);
    const int nw = (jend - jstart + 31) >> 5;   // 32-j windows (<=8)

    __shared__ __align__(16) unsigned short p2s[2][8][16][40];  // double buffer
    __shared__ __align__(16) float post_s[64];

    const int t = threadIdx.x;
    if (t < 64) post_s[t] = postp[t] * hsp[t & 7];

    const int lane = t & 63, w = t >> 6;
    const int iL = lane & 15, quad = lane >> 4;
    const int dW = w * 16 + iL;          // consumer d
    const int i_p = t & 15;              // producer i
    const int jj = t >> 4;               // producer j-group (0..15)
    const size_t ebase = (size_t)b * EPB + (size_t)(8 * tt * tt + 24 * tt) * 128;

    float linv[8];
#pragma unroll
    for (int h1 = 0; h1 < 8; ++h1)
        linv[h1] = 1.0f / lbuf[((size_t)(b * 128 + tt) * 8 + h1) * 16 + i_p];

    floatx4 y[8];
#pragma unroll
    for (int h2 = 0; h2 < 8; ++h2) y[h2] = (floatx4){0.f, 0.f, 0.f, 0.f};

    ushortx8 evc[2], evn[2];
    {   // prologue: load window 0's e-vectors (clamped)
        const int j0c = jstart + jj * 2;
        const int ja = min(j0c, jend - 1), jb2 = min(j0c + 1, jend - 1);
        evc[0] = *(const ushortx8*)(e16 + ebase + (size_t)(ja * 16 + i_p) * 8);
        evc[1] = *(const ushortx8*)(e16 + ebase + (size_t)(jb2 * 16 + i_p) * 8);
    }
    __syncthreads();

    for (int n = 0; n < nw; ++n) {
        const int jw0 = jstart + n * 32;
        {   // prefetch window n+1 (clamped; unused on last iter)
            const int j0n = jstart + (n + 1) * 32 + jj * 2;
            const int ja = min(j0n, jend - 1), jb2 = min(j0n + 1, jend - 1);
            evn[0] = *(const ushortx8*)(e16 + ebase + (size_t)(ja * 16 + i_p) * 8);
            evn[1] = *(const ushortx8*)(e16 + ebase + (size_t)(jb2 * 16 + i_p) * 8);
        }
        // postmix current window from registers
        float p2[2][8];
#pragma unroll
        for (int s = 0; s < 2; ++s) {
#pragma unroll
            for (int h2 = 0; h2 < 8; ++h2) p2[s][h2] = 0.f;
            const int j = jw0 + jj * 2 + s;
            if (j < jend) {
#pragma unroll
                for (int h1 = 0; h1 < 8; ++h1) {
                    const float e = __uint_as_float((unsigned int)(unsigned short)evc[s][h1] << 16)
                                    * linv[h1];
                    const float4 po0 = *(const float4*)(&post_s[h1 * 8]);
                    const float4 po1 = *(const float4*)(&post_s[h1 * 8 + 4]);
                    p2[s][0] = fmaf(e, po0.x, p2[s][0]);
                    p2[s][1] = fmaf(e, po0.y, p2[s][1]);
                    p2[s][2] = fmaf(e, po0.z, p2[s][2]);
                    p2[s][3] = fmaf(e, po0.w, p2[s][3]);
                    p2[s][4] = fmaf(e, po1.x, p2[s][4]);
                    p2[s][5] = fmaf(e, po1.y, p2[s][5]);
                    p2[s][6] = fmaf(e, po1.z, p2[s][6]);
                    p2[s][7] = fmaf(e, po1.w, p2[s][7]);
                }
            }
        }
        const int buf = n & 1;
#pragma unroll
        for (int h2 = 0; h2 < 8; ++h2)
            *(unsigned int*)(&p2s[buf][h2][i_p][jj * 2]) = pk2bf(p2[0][h2], p2[1][h2]);
        __syncthreads();   // single sync: writes(buf) done; reads of buf^1 from n-1 also done

        int jbv = jw0 + quad * 8;
        if (jbv > J - 8) jbv = J - 8;    // only masked cols; p2s=0 for them
#pragma unroll
        for (int h2 = 0; h2 < 8; ++h2) {
            const short8 aF = *(const short8*)(&p2s[buf][h2][iL][quad * 8]);
            const short8 bF = *(const short8*)(vt + ((size_t)(b * H + h2) * 64 + dW) * J + jbv);
            y[h2] = __builtin_amdgcn_mfma_f32_16x16x32_bf16(aF, bF, y[h2], 0, 0, 0);
        }
        evc[0] = evn[0]; evc[1] = evn[1];
    }

#pragma unroll
    for (int h2 = 0; h2 < 8; ++h2) {
#pragma unroll
        for (int r = 0; r < 4; ++r) {
            const int ii = i0 + quad * 4 + r;
            atomicAdd(ao + ((size_t)b * N + ii) * DIM + h2 * 64 + dW, y[h2][r]);
        }
    }
}

// ---------------- K3: output projection GEMM + bias (LDS dbuf, bf16 MFMA) -
__global__ __launch_bounds__(256)
void out_gemm(const float* __restrict__ ain, const unsigned short* __restrict__ WT,
              const float* __restrict__ bo, float* __restrict__ out)
{
    const int t = threadIdx.x;
    const int lane = t & 63, w = t >> 6;
    const int iL = lane & 15, quad = lane >> 4;
    const int mb = blockIdx.x * 64;
    const int n0 = blockIdx.y * 64;

    __shared__ __align__(16) unsigned short As[2][64][32];
    __shared__ __align__(16) unsigned short Bs[2][64][32];

    const int ar0 = t >> 3, as4 = (t & 7) * 4;
    const int br0 = t >> 2, bs8 = (t & 3) * 8;

    floatx4 acc[4];
#pragma unroll
    for (int ng = 0; ng < 4; ++ng) acc[ng] = (floatx4){0.f, 0.f, 0.f, 0.f};

    {
        const float4 v0 = *(const float4*)(ain + (size_t)(mb + ar0) * DIM + as4);
        const float4 v1 = *(const float4*)(ain + (size_t)(mb + ar0 + 32) * DIM + as4);
        ushortx4 o0 = { f2bf(v0.x), f2bf(v0.y), f2bf(v0.z), f2bf(v0.w) };
        ushortx4 o1 = { f2bf(v1.x), f2bf(v1.y), f2bf(v1.z), f2bf(v1.w) };
        *(ushortx4*)(&As[0][ar0][as4]) = o0;
        *(ushortx4*)(&As[0][ar0 + 32][as4]) = o1;
        *(ushortx8*)(&Bs[0][br0][bs8]) =
            *(const ushortx8*)(WT + (size_t)(n0 + br0) * DIM + bs8);
    }
    __syncthreads();

#pragma unroll
    for (int it = 0; it < 16; ++it) {
        const int buf = it & 1;
        if (it + 1 < 16) {
            const int k0 = (it + 1) * 32;
            const float4 v0 = *(const float4*)(ain + (size_t)(mb + ar0) * DIM + k0 + as4);
            const float4 v1 = *(const float4*)(ain + (size_t)(mb + ar0 + 32) * DIM + k0 + as4);
            const ushortx8 bv =
                *(const ushortx8*)(WT + (size_t)(n0 + br0) * DIM + k0 + bs8);
            ushortx4 o0 = { f2bf(v0.x), f2bf(v0.y), f2bf(v0.z), f2bf(v0.w) };
            ushortx4 o1 = { f2bf(v1.x), f2bf(v1.y), f2bf(v1.z), f2bf(v1.w) };
            *(ushortx4*)(&As[buf ^ 1][ar0][as4]) = o0;
            *(ushortx4*)(&As[buf ^ 1][ar0 + 32][as4]) = o1;
            *(ushortx8*)(&Bs[buf ^ 1][br0][bs8]) = bv;
        }
        const short8 af = *(const short8*)(&As[buf][w * 16 + iL][quad * 8]);
#pragma unroll
        for (int ng = 0; ng < 4; ++ng) {
            const short8 bf = *(const short8*)(&Bs[buf][ng * 16 + iL][quad * 8]);
            acc[ng] = __builtin_amdgcn_mfma_f32_16x16x32_bf16(af, bf, acc[ng], 0, 0, 0);
        }
        __syncthreads();
    }

    const int mbw = mb + w * 16;
#pragma unroll
    for (int ng = 0; ng < 4; ++ng) {
        const int n = n0 + ng * 16 + iL;
        const float bias = bo[n];
#pragma unroll
        for (int r = 0; r < 4; ++r) {
            const int m = mbw + quad * 4 + r;
            out[(size_t)m * DIM + n] = acc[ng][r] + bias;
        }
    }
}

extern "C" void kernel_launch(void* const* d_in, const int* in_sizes, int n_in,
                              void* d_out, int out_size, void* d_ws, size_t ws_size,
                              hipStream_t stream)
{
    (void)in_sizes; (void)n_in; (void)out_size; (void)ws_size;
    const float* x      = (const float*)d_in[0];
    const float* Wq     = (const float*)d_in[1];
    const float* Wk     = (const float*)d_in[2];
    const float* Wv     = (const float*)d_in[3];
    const float* mem_k  = (const float*)d_in[4];
    const float* mem_v  = (const float*)d_in[5];
    const float* pre_p  = (const float*)d_in[6];
    const float* post_p = (const float*)d_in[7];
    const float* hs     = (const float*)d_in[8];
    const float* Wo     = (const float*)d_in[9];
    const float* bo     = (const float*)d_in[10];
    float* out = (float*)d_out;

    constexpr size_t NAO  = (size_t)B * N * DIM;        // 2,097,152 f32
    constexpr size_t NLB  = (size_t)B * 128 * H * 16;   //    32,768 f32
    constexpr size_t NW   = (size_t)DIM * DIM;          //   262,144 u16 each
    constexpr size_t NQ   = (size_t)B * H * N * 64;     // 2,097,152 u16
    constexpr size_t NK   = (size_t)B * H * J * 64;     // 2,113,536 u16
    // total ws usage ~= 92 MB (e-buffer 68.7 MB)

    float* ws = (float*)d_ws;
    float* ao   = ws;
    float* lbuf = ao + NAO;
    unsigned short* wtq  = (unsigned short*)(lbuf + NLB);
    unsigned short* wtk  = wtq + NW;
    unsigned short* wtv  = wtk + NW;
    unsigned short* wto  = wtv + NW;
    unsigned short* q16  = wto + NW;
    unsigned short* k16  = q16 + NQ;
    unsigned short* v16  = k16 + NK;
    unsigned short* e16  = v16 + NK;

    wt_conv<<<dim3(8, 8, 4), 256, 0, stream>>>(Wq, Wk, Wv, Wo, wtq, wtk, wtv, wto);
    qkv_gemm<<<dim3(64, 8, 3), 256, 0, stream>>>(x, wtq, wtk, wtv, q16, k16, v16);
    memkv_copy<<<dim3(32), 256, 0, stream>>>(mem_k, mem_v, k16, v16);
    hipMemsetAsync(ao, 0, (NAO + NLB) * sizeof(float), stream);
    attn_scores<<<dim3(CMAX, 128, B), 256, 0, stream>>>(q16, k16, pre_p, lbuf, e16);
    attn_pv2<<<dim3(CMAX, 128, B), 256, 0, stream>>>(e16, v16, post_p, hs, lbuf, ao);
    out_gemm<<<dim3(64, 8), 256, 0, stream>>>(ao, wto, bo, out);
}